// Round 2
// baseline (751.802 us; speedup 1.0000x reference)
//
#include <hip/hip_runtime.h>
#include <hip/hip_bf16.h>

#define N_ENT 100000
#define N_USR 30000
#define N_TOTN 130000
#define N_RELC 32
#define DIM 64
#define NEDGE 500000
#define NA 1000000
#define SLOPE 0.01f
#define SCAN_NB 508   // ceil(130000/256)

__device__ __forceinline__ float wave_sum(float v){
  #pragma unroll
  for (int o = 32; o > 0; o >>= 1) v += __shfl_xor(v, o, 64);
  return v;
}
__device__ __forceinline__ float wave_max(float v){
  #pragma unroll
  for (int o = 32; o > 0; o >>= 1) v = fmaxf(v, __shfl_xor(v, o, 64));
  return v;
}

// m[r][j] = sum_d rel[r][d] * Wk[d][j]  (j in [0,128)) ; b[r] = sum_d Wkb[d]*rel[r][d]
__global__ void k_mrel(const float* __restrict__ rel, const float* __restrict__ Wk,
                       const float* __restrict__ Wkb, float* __restrict__ m, float* __restrict__ b){
  int idx = blockIdx.x*256 + threadIdx.x;
  if (idx < N_RELC*128){
    int r = idx >> 7, j = idx & 127;
    float s = 0.f;
    for (int d = 0; d < DIM; ++d) s += rel[r*DIM+d] * Wk[d*128+j];
    m[idx] = s;
  } else if (idx < N_RELC*128 + N_RELC){
    int r = idx - N_RELC*128;
    float s = 0.f;
    for (int d = 0; d < DIM; ++d) s += Wkb[d] * rel[r*DIM+d];
    b[r] = s;
  }
}

// h_list sorted -> segment offsets: off[s] = first edge with h >= s ; off[N_ENT] = E
__global__ void k_kgoff(const int* __restrict__ h_list, int* __restrict__ off){
  int e = blockIdx.x*256 + threadIdx.x;
  if (e > NEDGE) return;
  int hc = (e < NEDGE) ? h_list[e] : N_ENT;
  int hp = (e == 0) ? -1 : h_list[e-1];
  for (int s = hp+1; s <= hc; ++s) off[s] = e;
}

__global__ void k_hist(const int* __restrict__ a_row, int* __restrict__ cnt){
  int i = blockIdx.x*256 + threadIdx.x;
  if (i < NA) atomicAdd(&cnt[a_row[i]], 1);
}

__global__ void k_scan1(const int* __restrict__ cnt, int* __restrict__ part){
  __shared__ int sh[256];
  int idx = blockIdx.x*256 + threadIdx.x;
  sh[threadIdx.x] = (idx < N_TOTN) ? cnt[idx] : 0;
  __syncthreads();
  for (int o = 128; o > 0; o >>= 1){
    if (threadIdx.x < o) sh[threadIdx.x] += sh[threadIdx.x + o];
    __syncthreads();
  }
  if (threadIdx.x == 0) part[blockIdx.x] = sh[0];
}

__global__ void k_scan2(int* __restrict__ part){
  if (blockIdx.x == 0 && threadIdx.x == 0){
    int run = 0;
    for (int b = 0; b < SCAN_NB; ++b){ int t = part[b]; part[b] = run; run += t; }
  }
}

__global__ void k_scan3(int* __restrict__ cnt, const int* __restrict__ part, int* __restrict__ row_ptr){
  __shared__ int sh[256];
  int idx = blockIdx.x*256 + threadIdx.x;
  int v = (idx < N_TOTN) ? cnt[idx] : 0;
  sh[threadIdx.x] = v;
  __syncthreads();
  for (int o = 1; o < 256; o <<= 1){
    int a = (threadIdx.x >= o) ? sh[threadIdx.x - o] : 0;
    __syncthreads();
    sh[threadIdx.x] += a;
    __syncthreads();
  }
  int excl = part[blockIdx.x] + sh[threadIdx.x] - v;
  if (idx < N_TOTN){ row_ptr[idx] = excl; cnt[idx] = excl; }
  if (idx == 0) row_ptr[N_TOTN] = NA;
}

__global__ void k_fill(const int* __restrict__ a_row, const int* __restrict__ a_col,
                       const float* __restrict__ a_vals, int* __restrict__ pos,
                       int* __restrict__ csr_col, float* __restrict__ csr_val){
  int i = blockIdx.x*256 + threadIdx.x;
  if (i < NA){
    int r = a_row[i];
    int p = atomicAdd(&pos[r], 1);
    csr_col[p] = a_col[i];
    csr_val[p] = a_vals[i];
  }
}

// per-edge logits + leaky relu. one wave per edge (grid-stride). ent = all_embed (layer 1 only)
__global__ void __launch_bounds__(256) k_logits(const float* __restrict__ ent,
    const float* __restrict__ m, const float* __restrict__ bvec,
    const int* __restrict__ h_list, const int* __restrict__ t_list,
    const int* __restrict__ r_list, float* __restrict__ vals){
  __shared__ float msh[N_RELC*128];
  __shared__ float bsh[N_RELC];
  for (int i = threadIdx.x; i < N_RELC*128; i += 256) msh[i] = m[i];
  if (threadIdx.x < N_RELC) bsh[threadIdx.x] = bvec[threadIdx.x];
  __syncthreads();
  int lane = threadIdx.x & 63;
  int wave = (blockIdx.x*256 + threadIdx.x) >> 6;
  int nw = (gridDim.x*256) >> 6;
  for (int e = wave; e < NEDGE; e += nw){
    int ti = t_list[e], hi = h_list[e], r = r_list[e];
    float v = ent[(size_t)ti*DIM + lane] * msh[r*128 + lane]
            + ent[(size_t)hi*DIM + lane] * msh[r*128 + 64 + lane];
    v = wave_sum(v);
    if (lane == 0){
      float x = v + bsh[r];
      vals[e] = (x >= 0.f) ? x : SLOPE * x;
    }
  }
}

// segment softmax + weighted sum of tail rows. one wave per head entity, lane = dim.
__global__ void __launch_bounds__(256) k_kgagg(const float* __restrict__ ent,
    const float* __restrict__ vals, const int* __restrict__ off,
    const int* __restrict__ t_list, float* __restrict__ kg){
  int lane = threadIdx.x & 63;
  int wave = (blockIdx.x*256 + threadIdx.x) >> 6;
  int nw = (gridDim.x*256) >> 6;
  for (int s = wave; s < N_ENT; s += nw){
    int beg = off[s], end = off[s+1];
    float mx = -INFINITY;
    for (int e = beg + lane; e < end; e += 64) mx = fmaxf(mx, vals[e]);
    mx = wave_max(mx);
    float den = 0.f;
    for (int e = beg + lane; e < end; e += 64) den += __expf(vals[e] - mx);
    den = wave_sum(den);
    float inv = (end > beg) ? 1.f / den : 0.f;
    float acc = 0.f;
    for (int e = beg; e < end; ++e){
      float w = __expf(vals[e] - mx) * inv;
      acc += w * ent[(size_t)t_list[e]*DIM + lane];
    }
    kg[(size_t)s*DIM + lane] = acc;
  }
}

// CSR SpMM: ig_out = A @ [items_src ; users_src]. one wave per output row, lane = dim.
__global__ void __launch_bounds__(256) k_spmm(const int* __restrict__ row_ptr,
    const int* __restrict__ csr_col, const float* __restrict__ csr_val,
    const float* __restrict__ items_src, const float* __restrict__ users_src,
    float* __restrict__ collab, float* __restrict__ users_out){
  int lane = threadIdx.x & 63;
  int wave = (blockIdx.x*256 + threadIdx.x) >> 6;
  int nw = (gridDim.x*256) >> 6;
  for (int i = wave; i < N_TOTN; i += nw){
    int beg = row_ptr[i], end = row_ptr[i+1];
    float acc = 0.f;
    for (int e = beg; e < end; ++e){
      int c = csr_col[e];
      float v = csr_val[e];
      float s = (c < N_ENT) ? items_src[(size_t)c*DIM + lane]
                            : users_src[(size_t)(c - N_ENT)*DIM + lane];
      acc += v * s;
    }
    if (i < N_ENT) collab[(size_t)i*DIM + lane] = acc;
    else users_out[(size_t)(i - N_ENT)*DIM + lane] = acc;
  }
}

// dual = g*kg + (1-g)*collab, g = sigmoid(kg@Wa^T + collab@Wb^T). one wave per row.
__global__ void __launch_bounds__(256) k_gate(const float* __restrict__ kg,
    const float* __restrict__ collab, const float* __restrict__ Wa,
    const float* __restrict__ Wb, float* __restrict__ dual){
  __shared__ float Wash[64*65];
  __shared__ float Wbsh[64*65];
  for (int i = threadIdx.x; i < 4096; i += 256){
    int r = i >> 6, c = i & 63;
    Wash[r*65 + c] = Wa[i];
    Wbsh[r*65 + c] = Wb[i];
  }
  __syncthreads();
  int lane = threadIdx.x & 63;
  int wave = (blockIdx.x*256 + threadIdx.x) >> 6;
  int nw = (gridDim.x*256) >> 6;
  for (int row = wave; row < N_ENT; row += nw){
    float kv = kg[(size_t)row*DIM + lane];
    float cv = collab[(size_t)row*DIM + lane];
    float s = 0.f;
    #pragma unroll
    for (int j = 0; j < 64; ++j){
      s += __shfl(kv, j, 64) * Wash[lane*65 + j] + __shfl(cv, j, 64) * Wbsh[lane*65 + j];
    }
    float g = 1.f / (1.f + __expf(-s));
    dual[(size_t)row*DIM + lane] = g*kv + (1.f - g)*cv;
  }
}

// gather final user/item rows: base embed + layer1 + layer2 contributions
__global__ void k_gather(const float* __restrict__ all_embed,
    const float* __restrict__ users1, const float* __restrict__ users2,
    const float* __restrict__ collab1, const float* __restrict__ collab2,
    const int* __restrict__ user_ids, const int* __restrict__ item_ids,
    float* __restrict__ user_e, float* __restrict__ item_e){
  int idx = blockIdx.x*256 + threadIdx.x;
  if (idx >= 3072*DIM) return;
  int r = idx >> 6, d = idx & 63;
  if (r < 1024){
    int uid = user_ids[r];            // already offset by N_ENT
    int u = uid - N_ENT;
    user_e[idx] = all_embed[(size_t)uid*DIM + d] + users1[(size_t)u*DIM + d] + users2[(size_t)u*DIM + d];
  } else {
    int ii = r - 1024;
    int iid = item_ids[ii];
    item_e[(size_t)ii*DIM + d] = all_embed[(size_t)iid*DIM + d] + collab1[(size_t)iid*DIM + d] + collab2[(size_t)iid*DIM + d];
  }
}

// out[1024][2048] = user_e @ item_e^T, 16x16 tiles, K=64
__global__ void __launch_bounds__(256) k_out(const float* __restrict__ ue,
    const float* __restrict__ ie, float* __restrict__ out){
  __shared__ float ash[16*65];
  __shared__ float bsh[16*65];
  int tx = threadIdx.x & 15, ty = threadIdx.x >> 4;
  int row0 = blockIdx.y * 16, col0 = blockIdx.x * 16;
  for (int i = threadIdx.x; i < 1024; i += 256){
    int r = i >> 6, c = i & 63;
    ash[r*65 + c] = ue[(size_t)(row0 + r)*DIM + c];
    bsh[r*65 + c] = ie[(size_t)(col0 + r)*DIM + c];
  }
  __syncthreads();
  float s = 0.f;
  #pragma unroll
  for (int k = 0; k < 64; ++k) s += ash[ty*65 + k] * bsh[tx*65 + k];
  out[(size_t)(row0 + ty)*2048 + col0 + tx] = s;
}

extern "C" void kernel_launch(void* const* d_in, const int* in_sizes, int n_in,
                              void* d_out, int out_size, void* d_ws, size_t ws_size,
                              hipStream_t stream){
  const float* all_embed = (const float*)d_in[0];
  const float* rel_embed = (const float*)d_in[1];
  const float* Wk_w      = (const float*)d_in[2];
  const float* Wk_b      = (const float*)d_in[3];
  const float* Wa_w      = (const float*)d_in[4];
  const float* Wb_w      = (const float*)d_in[5];
  const float* a_vals    = (const float*)d_in[6];
  const int* user_ids   = (const int*)d_in[7];
  const int* item_ids   = (const int*)d_in[8];
  const int* h_list     = (const int*)d_in[9];
  const int* t_list     = (const int*)d_in[10];
  const int* r_list     = (const int*)d_in[11];
  const int* a_row      = (const int*)d_in[12];
  const int* a_col      = (const int*)d_in[13];
  float* out = (float*)d_out;

  char* p = (char*)d_ws;
  auto alloc = [&](size_t bytes)->void*{
    void* r = (void*)p;
    p += (bytes + 255) & ~(size_t)255;
    return r;
  };
  float* m_rel   = (float*)alloc((size_t)N_RELC*128*4);
  float* b_rel   = (float*)alloc((size_t)N_RELC*4);
  int*   kg_off  = (int*)  alloc((size_t)(N_ENT+1)*4);
  int*   cnt     = (int*)  alloc((size_t)N_TOTN*4);
  int*   row_ptr = (int*)  alloc((size_t)(N_TOTN+1)*4);
  int*   part    = (int*)  alloc((size_t)SCAN_NB*4);
  int*   csr_col = (int*)  alloc((size_t)NA*4);
  float* csr_val = (float*)alloc((size_t)NA*4);
  float* vals    = (float*)alloc((size_t)NEDGE*4);
  float* kg1     = (float*)alloc((size_t)N_ENT*DIM*4);
  float* collab1 = (float*)alloc((size_t)N_ENT*DIM*4);
  float* dual1   = (float*)alloc((size_t)N_ENT*DIM*4);
  float* users1  = (float*)alloc((size_t)N_USR*DIM*4);
  float* users2  = (float*)alloc((size_t)N_USR*DIM*4);
  float* user_e  = (float*)alloc((size_t)1024*DIM*4);
  float* item_e  = (float*)alloc((size_t)2048*DIM*4);
  float* collab2 = kg1;   // kg1 dead after k_gate; alias to save 25.6 MB

  hipMemsetAsync(cnt, 0, (size_t)N_TOTN*4, stream);
  k_mrel<<<17, 256, 0, stream>>>(rel_embed, Wk_w, Wk_b, m_rel, b_rel);
  k_kgoff<<<(NEDGE + 1 + 255)/256, 256, 0, stream>>>(h_list, kg_off);
  k_hist<<<(NA + 255)/256, 256, 0, stream>>>(a_row, cnt);
  k_scan1<<<SCAN_NB, 256, 0, stream>>>(cnt, part);
  k_scan2<<<1, 64, 0, stream>>>(part);
  k_scan3<<<SCAN_NB, 256, 0, stream>>>(cnt, part, row_ptr);
  k_fill<<<(NA + 255)/256, 256, 0, stream>>>(a_row, a_col, a_vals, cnt, csr_col, csr_val);

  // layer 1 (full)
  k_logits<<<2048, 256, 0, stream>>>(all_embed, m_rel, b_rel, h_list, t_list, r_list, vals);
  k_kgagg<<<4096, 256, 0, stream>>>(all_embed, vals, kg_off, t_list, kg1);
  k_spmm<<<4096, 256, 0, stream>>>(row_ptr, csr_col, csr_val,
      all_embed, all_embed + (size_t)N_ENT*DIM, collab1, users1);
  k_gate<<<4096, 256, 0, stream>>>(kg1, collab1, Wa_w, Wb_w, dual1);

  // layer 2: only the collaborative SpMM feeds the output (KG branch is dead code)
  k_spmm<<<4096, 256, 0, stream>>>(row_ptr, csr_col, csr_val,
      dual1, users1, collab2, users2);

  k_gather<<<(3072*DIM + 255)/256, 256, 0, stream>>>(all_embed, users1, users2,
      collab1, collab2, user_ids, item_ids, user_e, item_e);
  dim3 grid_out(2048/16, 1024/16);
  k_out<<<grid_out, 256, 0, stream>>>(user_e, item_e, out);
}

// Round 3
// 451.183 us; speedup vs baseline: 1.6663x; 1.6663x over previous
//
#include <hip/hip_runtime.h>
#include <hip/hip_bf16.h>

#define N_ENT 100000
#define N_USR 30000
#define N_TOTN 130000
#define N_RELC 32
#define DIM 64
#define NEDGE 500000
#define NA 1000000
#define SLOPE 0.01f
#define SCAN_NB 508   // ceil(130000/256)

__device__ __forceinline__ float grp_sum16(float v){
  v += __shfl_xor(v, 8, 64);
  v += __shfl_xor(v, 4, 64);
  v += __shfl_xor(v, 2, 64);
  v += __shfl_xor(v, 1, 64);
  return v;
}
__device__ __forceinline__ float grp_max16(float v){
  v = fmaxf(v, __shfl_xor(v, 8, 64));
  v = fmaxf(v, __shfl_xor(v, 4, 64));
  v = fmaxf(v, __shfl_xor(v, 2, 64));
  v = fmaxf(v, __shfl_xor(v, 1, 64));
  return v;
}

// m[r][j] = sum_d rel[r][d] * Wk[d][j]  (j in [0,128)) ; b[r] = sum_d Wkb[d]*rel[r][d]
__global__ void k_mrel(const float* __restrict__ rel, const float* __restrict__ Wk,
                       const float* __restrict__ Wkb, float* __restrict__ m, float* __restrict__ b){
  int idx = blockIdx.x*256 + threadIdx.x;
  if (idx < N_RELC*128){
    int r = idx >> 7, j = idx & 127;
    float s = 0.f;
    for (int d = 0; d < DIM; ++d) s += rel[r*DIM+d] * Wk[d*128+j];
    m[idx] = s;
  } else if (idx < N_RELC*128 + N_RELC){
    int r = idx - N_RELC*128;
    float s = 0.f;
    for (int d = 0; d < DIM; ++d) s += Wkb[d] * rel[r*DIM+d];
    b[r] = s;
  }
}

// h_list sorted -> segment offsets: off[s] = first edge with h >= s ; off[N_ENT] = E
__global__ void k_kgoff(const int* __restrict__ h_list, int* __restrict__ off){
  int e = blockIdx.x*256 + threadIdx.x;
  if (e > NEDGE) return;
  int hc = (e < NEDGE) ? h_list[e] : N_ENT;
  int hp = (e == 0) ? -1 : h_list[e-1];
  for (int s = hp+1; s <= hc; ++s) off[s] = e;
}

__global__ void k_hist(const int* __restrict__ a_row, int* __restrict__ cnt){
  int i = blockIdx.x*256 + threadIdx.x;
  if (i < NA) atomicAdd(&cnt[a_row[i]], 1);
}

__global__ void k_scan1(const int* __restrict__ cnt, int* __restrict__ part){
  __shared__ int sh[256];
  int idx = blockIdx.x*256 + threadIdx.x;
  sh[threadIdx.x] = (idx < N_TOTN) ? cnt[idx] : 0;
  __syncthreads();
  for (int o = 128; o > 0; o >>= 1){
    if (threadIdx.x < o) sh[threadIdx.x] += sh[threadIdx.x + o];
    __syncthreads();
  }
  if (threadIdx.x == 0) part[blockIdx.x] = sh[0];
}

// 512-thread single-block exclusive scan of the 508 partials (replaces serial 1-thread scan)
__global__ void k_scan2(int* __restrict__ part){
  __shared__ int sh[512];
  int t = threadIdx.x;
  int v = (t < SCAN_NB) ? part[t] : 0;
  sh[t] = v;
  __syncthreads();
  for (int o = 1; o < 512; o <<= 1){
    int a = (t >= o) ? sh[t - o] : 0;
    __syncthreads();
    sh[t] += a;
    __syncthreads();
  }
  if (t < SCAN_NB) part[t] = sh[t] - v;   // exclusive
}

__global__ void k_scan3(int* __restrict__ cnt, const int* __restrict__ part, int* __restrict__ row_ptr){
  __shared__ int sh[256];
  int idx = blockIdx.x*256 + threadIdx.x;
  int v = (idx < N_TOTN) ? cnt[idx] : 0;
  sh[threadIdx.x] = v;
  __syncthreads();
  for (int o = 1; o < 256; o <<= 1){
    int a = (threadIdx.x >= o) ? sh[threadIdx.x - o] : 0;
    __syncthreads();
    sh[threadIdx.x] += a;
    __syncthreads();
  }
  int excl = part[blockIdx.x] + sh[threadIdx.x] - v;
  if (idx < N_TOTN){ row_ptr[idx] = excl; cnt[idx] = excl; }
  if (idx == 0) row_ptr[N_TOTN] = NA;
}

__global__ void k_fill(const int* __restrict__ a_row, const int* __restrict__ a_col,
                       const float* __restrict__ a_vals, int* __restrict__ pos,
                       int* __restrict__ csr_col, float* __restrict__ csr_val){
  int i = blockIdx.x*256 + threadIdx.x;
  if (i < NA){
    int r = a_row[i];
    int p = atomicAdd(&pos[r], 1);
    csr_col[p] = a_col[i];
    csr_val[p] = a_vals[i];
  }
}

// per-edge logits + leaky relu. 16-lane group per edge, float4 per lane.
__global__ void __launch_bounds__(256) k_logits(const float4* __restrict__ ent4,
    const float4* __restrict__ m4, const float* __restrict__ bvec,
    const int* __restrict__ h_list, const int* __restrict__ t_list,
    const int* __restrict__ r_list, float* __restrict__ vals){
  __shared__ float4 msh[N_RELC*32];
  __shared__ float bsh[N_RELC];
  for (int i = threadIdx.x; i < N_RELC*32; i += 256) msh[i] = m4[i];
  if (threadIdx.x < N_RELC) bsh[threadIdx.x] = bvec[threadIdx.x];
  __syncthreads();
  int sub = threadIdx.x & 15;
  int grp = (blockIdx.x*256 + threadIdx.x) >> 4;
  int ng = (gridDim.x*256) >> 4;
  for (int e = grp; e < NEDGE; e += ng){
    int ti = t_list[e], hi = h_list[e], r = r_list[e];
    float4 t4 = ent4[(size_t)ti*16 + sub];
    float4 h4 = ent4[(size_t)hi*16 + sub];
    float4 mt = msh[r*32 + sub];
    float4 mh = msh[r*32 + 16 + sub];
    float v = t4.x*mt.x + t4.y*mt.y + t4.z*mt.z + t4.w*mt.w
            + h4.x*mh.x + h4.y*mh.y + h4.z*mh.z + h4.w*mh.w;
    v = grp_sum16(v);
    if (sub == 0){
      float x = v + bsh[r];
      vals[e] = (x >= 0.f) ? x : SLOPE * x;
    }
  }
}

// segment softmax + weighted sum of tail rows. 16-lane group per head entity.
__global__ void __launch_bounds__(256) k_kgagg(const float4* __restrict__ ent4,
    const float* __restrict__ vals, const int* __restrict__ off,
    const int* __restrict__ t_list, float4* __restrict__ kg4){
  int sub = threadIdx.x & 15;
  int grp = (blockIdx.x*256 + threadIdx.x) >> 4;
  int ng = (gridDim.x*256) >> 4;
  for (int s = grp; s < N_ENT; s += ng){
    int beg = off[s], end = off[s+1];
    float mx = -INFINITY;
    for (int e = beg + sub; e < end; e += 16) mx = fmaxf(mx, vals[e]);
    mx = grp_max16(mx);
    float den = 0.f;
    for (int e = beg + sub; e < end; e += 16) den += __expf(vals[e] - mx);
    den = grp_sum16(den);
    float inv = (end > beg) ? 1.f / den : 0.f;
    float4 acc = {0.f,0.f,0.f,0.f};
    for (int e = beg; e < end; ++e){
      float w = __expf(vals[e] - mx) * inv;
      float4 t4 = ent4[(size_t)t_list[e]*16 + sub];
      acc.x += w*t4.x; acc.y += w*t4.y; acc.z += w*t4.z; acc.w += w*t4.w;
    }
    kg4[(size_t)s*16 + sub] = acc;
  }
}

// CSR SpMM: out = A @ src, src is one contiguous [N_TOT][64] table. 16-lane group per row.
__global__ void __launch_bounds__(256) k_spmm(const int* __restrict__ row_ptr,
    const int* __restrict__ csr_col, const float* __restrict__ csr_val,
    const float4* __restrict__ src4, float4* __restrict__ items_out,
    float4* __restrict__ users_out){
  int sub = threadIdx.x & 15;
  int grp = (blockIdx.x*256 + threadIdx.x) >> 4;
  int ng = (gridDim.x*256) >> 4;
  for (int i = grp; i < N_TOTN; i += ng){
    int beg = row_ptr[i], end = row_ptr[i+1];
    float4 acc = {0.f,0.f,0.f,0.f};
    for (int e = beg; e < end; ++e){
      int c = csr_col[e];
      float v = csr_val[e];
      float4 s = src4[(size_t)c*16 + sub];
      acc.x += v*s.x; acc.y += v*s.y; acc.z += v*s.z; acc.w += v*s.w;
    }
    if (i < N_ENT) items_out[(size_t)i*16 + sub] = acc;
    else users_out[(size_t)(i - N_ENT)*16 + sub] = acc;
  }
}

// dual = g*kg + (1-g)*collab, g = sigmoid(kg@Wa^T + collab@Wb^T).
// LDS-tiled fp32 GEMM: X=[kg|collab] (64 rows x 128), W staged transposed, 4x4 micro-tiles.
__global__ void __launch_bounds__(256) k_gate(const float* __restrict__ kg,
    const float* __restrict__ collab, const float* __restrict__ Wa,
    const float* __restrict__ Wb, float* __restrict__ dual){
  __shared__ float Xsh[64][129];   // rows x 128 inputs, +1 pad -> worst 2-way (free)
  __shared__ float Wsh[128][65];   // [k][c], +1 pad
  int row0 = blockIdx.x * 64;
  // W: coalesced global read, transposed LDS write (pad keeps writes conflict-free)
  for (int i = threadIdx.x; i < 64*64; i += 256){
    int a = i >> 6, j = i & 63;            // a = output idx, j = input idx
    Wsh[j][a] = Wa[i];
    Wsh[64 + j][a] = Wb[i];
  }
  for (int i = threadIdx.x; i < 64*128; i += 256){
    int r = i >> 7, c = i & 127;
    int row = row0 + r;
    float v = 0.f;
    if (row < N_ENT) v = (c < 64) ? kg[(size_t)row*64 + c] : collab[(size_t)row*64 + (c - 64)];
    Xsh[r][c] = v;
  }
  __syncthreads();
  int ct = threadIdx.x & 15, rt = threadIdx.x >> 4;
  int r0 = rt * 4, c0 = ct * 4;
  float acc[4][4] = {};
  for (int k = 0; k < 128; ++k){
    float w0 = Wsh[k][c0], w1 = Wsh[k][c0+1], w2 = Wsh[k][c0+2], w3 = Wsh[k][c0+3];
    #pragma unroll
    for (int i = 0; i < 4; ++i){
      float x = Xsh[r0+i][k];
      acc[i][0] += x*w0; acc[i][1] += x*w1; acc[i][2] += x*w2; acc[i][3] += x*w3;
    }
  }
  #pragma unroll
  for (int i = 0; i < 4; ++i){
    int row = row0 + r0 + i;
    if (row < N_ENT){
      float4 o;
      #pragma unroll
      for (int j = 0; j < 4; ++j){
        int c = c0 + j;
        float g = 1.f / (1.f + __expf(-acc[i][j]));
        float kv = Xsh[r0+i][c];
        float cv = Xsh[r0+i][64 + c];
        (&o.x)[j] = g*kv + (1.f - g)*cv;
      }
      *(float4*)&dual[(size_t)row*64 + c0] = o;
    }
  }
}

// gather final user/item rows: base embed + layer1 + layer2 contributions
__global__ void k_gather(const float4* __restrict__ all_embed4,
    const float4* __restrict__ users1, const float4* __restrict__ users2,
    const float4* __restrict__ collab1, const float4* __restrict__ collab2,
    const int* __restrict__ user_ids, const int* __restrict__ item_ids,
    float4* __restrict__ user_e, float4* __restrict__ item_e){
  int idx = blockIdx.x*256 + threadIdx.x;
  if (idx >= 3072*16) return;
  int r = idx >> 4, d = idx & 15;
  if (r < 1024){
    int uid = user_ids[r];            // already offset by N_ENT
    int u = uid - N_ENT;
    float4 a = all_embed4[(size_t)uid*16 + d];
    float4 b = users1[(size_t)u*16 + d];
    float4 c = users2[(size_t)u*16 + d];
    float4 o = {a.x+b.x+c.x, a.y+b.y+c.y, a.z+b.z+c.z, a.w+b.w+c.w};
    user_e[idx] = o;
  } else {
    int ii = r - 1024;
    int iid = item_ids[ii];
    float4 a = all_embed4[(size_t)iid*16 + d];
    float4 b = collab1[(size_t)iid*16 + d];
    float4 c = collab2[(size_t)iid*16 + d];
    float4 o = {a.x+b.x+c.x, a.y+b.y+c.y, a.z+b.z+c.z, a.w+b.w+c.w};
    item_e[(size_t)ii*16 + d] = o;
  }
}

// out[1024][2048] = user_e @ item_e^T, 32x32 tiles, 2x2 micro-tile, K=64
__global__ void __launch_bounds__(256) k_out(const float* __restrict__ ue,
    const float* __restrict__ ie, float* __restrict__ out){
  __shared__ float ash[32][65];
  __shared__ float bsh[32][65];
  int row0 = blockIdx.y * 32, col0 = blockIdx.x * 32;
  for (int i = threadIdx.x; i < 32*64; i += 256){
    int r = i >> 6, c = i & 63;
    ash[r][c] = ue[(size_t)(row0 + r)*DIM + c];
    bsh[r][c] = ie[(size_t)(col0 + r)*DIM + c];
  }
  __syncthreads();
  int tx = threadIdx.x & 15, ty = threadIdx.x >> 4;
  int r0 = ty*2, c0 = tx*2;
  float a00=0.f, a01=0.f, a10=0.f, a11=0.f;
  #pragma unroll
  for (int k = 0; k < 64; ++k){
    float x0 = ash[r0][k], x1 = ash[r0+1][k];
    float y0 = bsh[c0][k], y1 = bsh[c0+1][k];
    a00 += x0*y0; a01 += x0*y1; a10 += x1*y0; a11 += x1*y1;
  }
  float2 o0 = {a00, a01}, o1 = {a10, a11};
  *(float2*)&out[(size_t)(row0 + r0)*2048 + col0 + c0] = o0;
  *(float2*)&out[(size_t)(row0 + r0 + 1)*2048 + col0 + c0] = o1;
}

extern "C" void kernel_launch(void* const* d_in, const int* in_sizes, int n_in,
                              void* d_out, int out_size, void* d_ws, size_t ws_size,
                              hipStream_t stream){
  const float* all_embed = (const float*)d_in[0];
  const float* rel_embed = (const float*)d_in[1];
  const float* Wk_w      = (const float*)d_in[2];
  const float* Wk_b      = (const float*)d_in[3];
  const float* Wa_w      = (const float*)d_in[4];
  const float* Wb_w      = (const float*)d_in[5];
  const float* a_vals    = (const float*)d_in[6];
  const int* user_ids   = (const int*)d_in[7];
  const int* item_ids   = (const int*)d_in[8];
  const int* h_list     = (const int*)d_in[9];
  const int* t_list     = (const int*)d_in[10];
  const int* r_list     = (const int*)d_in[11];
  const int* a_row      = (const int*)d_in[12];
  const int* a_col      = (const int*)d_in[13];
  float* out = (float*)d_out;

  char* p = (char*)d_ws;
  auto alloc = [&](size_t bytes)->void*{
    void* r = (void*)p;
    p += (bytes + 255) & ~(size_t)255;
    return r;
  };
  float* m_rel   = (float*)alloc((size_t)N_RELC*128*4);
  float* b_rel   = (float*)alloc((size_t)N_RELC*4);
  int*   kg_off  = (int*)  alloc((size_t)(N_ENT+1)*4);
  int*   cnt     = (int*)  alloc((size_t)N_TOTN*4);
  int*   row_ptr = (int*)  alloc((size_t)(N_TOTN+1)*4);
  int*   part    = (int*)  alloc((size_t)SCAN_NB*4);
  int*   csr_col = (int*)  alloc((size_t)NA*4);
  float* csr_val = (float*)alloc((size_t)NA*4);
  float* vals    = (float*)alloc((size_t)NEDGE*4);
  float* kg1     = (float*)alloc((size_t)N_ENT*DIM*4);
  float* collab1 = (float*)alloc((size_t)N_ENT*DIM*4);
  float* x2      = (float*)alloc((size_t)N_TOTN*DIM*4);  // [dual1 ; users1] contiguous
  float* users2  = (float*)alloc((size_t)N_USR*DIM*4);
  float* user_e  = (float*)alloc((size_t)1024*DIM*4);
  float* item_e  = (float*)alloc((size_t)2048*DIM*4);
  float* collab2 = kg1;                       // kg1 dead after k_gate
  float* users1  = x2 + (size_t)N_ENT*DIM;    // spmm-1 writes users here
  float* dual1   = x2;                        // k_gate writes dual here

  hipMemsetAsync(cnt, 0, (size_t)N_TOTN*4, stream);
  k_mrel<<<17, 256, 0, stream>>>(rel_embed, Wk_w, Wk_b, m_rel, b_rel);
  k_kgoff<<<(NEDGE + 1 + 255)/256, 256, 0, stream>>>(h_list, kg_off);
  k_hist<<<(NA + 255)/256, 256, 0, stream>>>(a_row, cnt);
  k_scan1<<<SCAN_NB, 256, 0, stream>>>(cnt, part);
  k_scan2<<<1, 512, 0, stream>>>(part);
  k_scan3<<<SCAN_NB, 256, 0, stream>>>(cnt, part, row_ptr);
  k_fill<<<(NA + 255)/256, 256, 0, stream>>>(a_row, a_col, a_vals, cnt, csr_col, csr_val);

  // layer 1
  k_logits<<<2048, 256, 0, stream>>>((const float4*)all_embed, (const float4*)m_rel,
      b_rel, h_list, t_list, r_list, vals);
  k_kgagg<<<2048, 256, 0, stream>>>((const float4*)all_embed, vals, kg_off, t_list,
      (float4*)kg1);
  k_spmm<<<2048, 256, 0, stream>>>(row_ptr, csr_col, csr_val,
      (const float4*)all_embed, (float4*)collab1, (float4*)users1);
  k_gate<<<(N_ENT + 63)/64, 256, 0, stream>>>(kg1, collab1, Wa_w, Wb_w, dual1);

  // layer 2: only the collaborative SpMM feeds the output (KG branch is dead code)
  k_spmm<<<2048, 256, 0, stream>>>(row_ptr, csr_col, csr_val,
      (const float4*)x2, (float4*)collab2, (float4*)users2);

  k_gather<<<(3072*16 + 255)/256, 256, 0, stream>>>((const float4*)all_embed,
      (const float4*)users1, (const float4*)users2, (const float4*)collab1,
      (const float4*)collab2, user_ids, item_ids, (float4*)user_e, (float4*)item_e);
  dim3 grid_out(2048/32, 1024/32);
  k_out<<<grid_out, 256, 0, stream>>>(user_e, item_e, out);
}

// Round 4
// 321.825 us; speedup vs baseline: 2.3361x; 1.4020x over previous
//
#include <hip/hip_runtime.h>
#include <hip/hip_bf16.h>

#define N_ENT 100000
#define N_USR 30000
#define N_TOTN 130000
#define N_RELC 32
#define DIM 64
#define NEDGE 500000
#define NA 1000000
#define SLOPE 0.01f
#define SCAN_NB 508   // ceil(130000/256)

typedef unsigned char u8;
typedef unsigned long long u64;

__device__ __forceinline__ float grp_sum16(float v){
  v += __shfl_xor(v, 8, 64);
  v += __shfl_xor(v, 4, 64);
  v += __shfl_xor(v, 2, 64);
  v += __shfl_xor(v, 1, 64);
  return v;
}

// m[r][j] = sum_d rel[r][d] * Wk[d][j]  (j in [0,128)) ; b[r] = sum_d Wkb[d]*rel[r][d]
__global__ void k_mrel(const float* __restrict__ rel, const float* __restrict__ Wk,
                       const float* __restrict__ Wkb, float* __restrict__ m, float* __restrict__ b){
  int idx = blockIdx.x*256 + threadIdx.x;
  if (idx < N_RELC*128){
    int r = idx >> 7, j = idx & 127;
    float s = 0.f;
    for (int d = 0; d < DIM; ++d) s += rel[r*DIM+d] * Wk[d*128+j];
    m[idx] = s;
  } else if (idx < N_RELC*128 + N_RELC){
    int r = idx - N_RELC*128;
    float s = 0.f;
    for (int d = 0; d < DIM; ++d) s += Wkb[d] * rel[r*DIM+d];
    b[r] = s;
  }
}

// h_list sorted -> segment offsets
__global__ void k_kgoff(const int* __restrict__ h_list, int* __restrict__ off){
  int e = blockIdx.x*256 + threadIdx.x;
  if (e > NEDGE) return;
  int hc = (e < NEDGE) ? h_list[e] : N_ENT;
  int hp = (e == 0) ? -1 : h_list[e-1];
  for (int s = hp+1; s <= hc; ++s) off[s] = e;
}

// flag the 3072 output rows
__global__ void k_r2(const int* __restrict__ user_ids, const int* __restrict__ item_ids,
                     u8* __restrict__ r2_item, u8* __restrict__ r2_user){
  int i = blockIdx.x*256 + threadIdx.x;
  if (i < 1024) r2_user[user_ids[i] - N_ENT] = 1;
  else if (i < 3072) r2_item[item_ids[i - 1024]] = 1;
}

// mark columns needed as spmm-2 inputs (neighbors of output rows)
__global__ void k_mark(const int* __restrict__ a_row, const int* __restrict__ a_col,
                       const u8* __restrict__ r2_item, const u8* __restrict__ r2_user,
                       u8* __restrict__ need_d, u8* __restrict__ need_u){
  int i = blockIdx.x*256 + threadIdx.x;
  if (i >= NA) return;
  int r = a_row[i];
  bool f = (r < N_ENT) ? (r2_item[r] != 0) : (r2_user[r - N_ENT] != 0);
  if (f){
    int c = a_col[i];
    if (c < N_ENT) need_d[c] = 1;
    else need_u[c - N_ENT] = 1;
  }
}

// build compact row lists (ballot-aggregated append) + row_need flags for CSR restriction
__global__ void k_lists(const u8* __restrict__ need_d, const u8* __restrict__ need_u,
                        const u8* __restrict__ r2_item, const u8* __restrict__ r2_user,
                        u8* __restrict__ row_need, int* __restrict__ list_gate,
                        int* __restrict__ list_s1, int* __restrict__ counters){
  int i = blockIdx.x*256 + threadIdx.x;
  int lane = threadIdx.x & 63;
  bool pg = false, ps = false;
  if (i < N_TOTN){
    if (i < N_ENT){ pg = need_d[i] != 0; ps = pg || (r2_item[i] != 0); }
    else { int u = i - N_ENT; ps = (need_u[u] != 0) || (r2_user[u] != 0); }
    row_need[i] = ps ? 1 : 0;
  }
  u64 mg = __ballot(pg);
  if (mg){
    int leader = __ffsll(mg) - 1;
    int base = 0;
    if (lane == leader) base = atomicAdd(&counters[0], __popcll(mg));
    base = __shfl(base, leader, 64);
    if (pg) list_gate[base + __popcll(mg & ((1ull << lane) - 1))] = i;
  }
  u64 ms = __ballot(ps);
  if (ms){
    int leader = __ffsll(ms) - 1;
    int base = 0;
    if (lane == leader) base = atomicAdd(&counters[1], __popcll(ms));
    base = __shfl(base, leader, 64);
    if (ps) list_s1[base + __popcll(ms & ((1ull << lane) - 1))] = i;
  }
}

__global__ void k_hist(const int* __restrict__ a_row, const u8* __restrict__ row_need,
                       int* __restrict__ cnt){
  int i = blockIdx.x*256 + threadIdx.x;
  if (i < NA){
    int r = a_row[i];
    if (row_need[r]) atomicAdd(&cnt[r], 1);
  }
}

__global__ void k_scan1(const int* __restrict__ cnt, int* __restrict__ part){
  __shared__ int sh[256];
  int idx = blockIdx.x*256 + threadIdx.x;
  sh[threadIdx.x] = (idx < N_TOTN) ? cnt[idx] : 0;
  __syncthreads();
  for (int o = 128; o > 0; o >>= 1){
    if (threadIdx.x < o) sh[threadIdx.x] += sh[threadIdx.x + o];
    __syncthreads();
  }
  if (threadIdx.x == 0) part[blockIdx.x] = sh[0];
}

__global__ void k_scan2(int* __restrict__ part){
  __shared__ int sh[512];
  int t = threadIdx.x;
  int v = (t < SCAN_NB) ? part[t] : 0;
  sh[t] = v;
  __syncthreads();
  for (int o = 1; o < 512; o <<= 1){
    int a = (t >= o) ? sh[t - o] : 0;
    __syncthreads();
    sh[t] += a;
    __syncthreads();
  }
  if (t < SCAN_NB) part[t] = sh[t] - v;   // exclusive
}

__global__ void k_scan3(int* __restrict__ cnt, const int* __restrict__ part, int* __restrict__ row_ptr){
  __shared__ int sh[256];
  int idx = blockIdx.x*256 + threadIdx.x;
  int v = (idx < N_TOTN) ? cnt[idx] : 0;
  sh[threadIdx.x] = v;
  __syncthreads();
  for (int o = 1; o < 256; o <<= 1){
    int a = (threadIdx.x >= o) ? sh[threadIdx.x - o] : 0;
    __syncthreads();
    sh[threadIdx.x] += a;
    __syncthreads();
  }
  int excl = part[blockIdx.x] + sh[threadIdx.x] - v;
  if (idx < N_TOTN){ row_ptr[idx] = excl; cnt[idx] = excl; }
  if (idx == 0) row_ptr[N_TOTN] = 0;   // unused sentinel; real ends come from per-row cnt
}

__global__ void k_fill(const int* __restrict__ a_row, const int* __restrict__ a_col,
                       const float* __restrict__ a_vals, const u8* __restrict__ row_need,
                       int* __restrict__ pos, int* __restrict__ csr_col, float* __restrict__ csr_val){
  int i = blockIdx.x*256 + threadIdx.x;
  if (i < NA){
    int r = a_row[i];
    if (row_need[r]){
      int p = atomicAdd(&pos[r], 1);
      csr_col[p] = a_col[i];
      csr_val[p] = a_vals[i];
    }
  }
}

// fused edge-logits + online segment softmax + weighted tail aggregation.
// 16-lane group per head entity from list_gate.
__global__ void __launch_bounds__(256) k_att(const float4* __restrict__ ent4,
    const float4* __restrict__ m4, const float* __restrict__ bvec,
    const int* __restrict__ off, const int* __restrict__ t_list,
    const int* __restrict__ r_list, const int* __restrict__ list,
    const int* __restrict__ counters, float4* __restrict__ kg4){
  __shared__ float4 msh[N_RELC*32];
  __shared__ float bsh[N_RELC];
  for (int i = threadIdx.x; i < N_RELC*32; i += 256) msh[i] = m4[i];
  if (threadIdx.x < N_RELC) bsh[threadIdx.x] = bvec[threadIdx.x];
  __syncthreads();
  int n = counters[0];
  int sub = threadIdx.x & 15;
  int grp = (blockIdx.x*256 + threadIdx.x) >> 4;
  int ng = (gridDim.x*256) >> 4;
  for (int idx = grp; idx < n; idx += ng){
    int s = list[idx];
    int beg = off[s], end = off[s+1];
    float4 h4 = ent4[(size_t)s*16 + sub];
    float mx = -INFINITY, l = 0.f;
    float4 acc = {0.f,0.f,0.f,0.f};
    for (int e = beg; e < end; ++e){
      int r = r_list[e], ti = t_list[e];
      float4 t4 = ent4[(size_t)ti*16 + sub];
      float4 mt = msh[r*32 + sub];
      float4 mh = msh[r*32 + 16 + sub];
      float v = t4.x*mt.x + t4.y*mt.y + t4.z*mt.z + t4.w*mt.w
              + h4.x*mh.x + h4.y*mh.y + h4.z*mh.z + h4.w*mh.w;
      v = grp_sum16(v) + bsh[r];
      v = (v >= 0.f) ? v : SLOPE * v;
      float mn = fmaxf(mx, v);
      float al = __expf(mx - mn);   // first iter: exp(-inf)=0
      float w  = __expf(v - mn);
      l = l*al + w;
      acc.x = acc.x*al + w*t4.x; acc.y = acc.y*al + w*t4.y;
      acc.z = acc.z*al + w*t4.z; acc.w = acc.w*al + w*t4.w;
      mx = mn;
    }
    float inv = (end > beg) ? 1.f / l : 0.f;
    float4 o = {acc.x*inv, acc.y*inv, acc.z*inv, acc.w*inv};
    kg4[(size_t)s*16 + sub] = o;
  }
}

// restricted CSR SpMM layer 1: rows from list_s1, src = all_embed (contiguous table).
// items -> collab1 ; users -> x2 rows >= N_ENT (users1 lives inside x2).
__global__ void __launch_bounds__(256) k_spmm1(const int* __restrict__ row_ptr,
    const int* __restrict__ cnt_end, const int* __restrict__ csr_col,
    const float* __restrict__ csr_val, const float4* __restrict__ src4,
    const int* __restrict__ list, const int* __restrict__ counters,
    float4* __restrict__ collab4, float4* __restrict__ x2_4){
  int n = counters[1];
  int sub = threadIdx.x & 15;
  int grp = (blockIdx.x*256 + threadIdx.x) >> 4;
  int ng = (gridDim.x*256) >> 4;
  for (int idx = grp; idx < n; idx += ng){
    int i = list[idx];
    int beg = row_ptr[i], end = cnt_end[i];
    float4 acc = {0.f,0.f,0.f,0.f};
    for (int e = beg; e < end; ++e){
      int c = csr_col[e];
      float v = csr_val[e];
      float4 s = src4[(size_t)c*16 + sub];
      acc.x += v*s.x; acc.y += v*s.y; acc.z += v*s.z; acc.w += v*s.w;
    }
    if (i < N_ENT) collab4[(size_t)i*16 + sub] = acc;
    else x2_4[(size_t)i*16 + sub] = acc;
  }
}

// gate over list rows: dual = g*kg + (1-g)*collab -> x2 rows < N_ENT
__global__ void __launch_bounds__(256) k_gate(const float* __restrict__ kg,
    const float* __restrict__ collab, const float* __restrict__ Wa,
    const float* __restrict__ Wb, float* __restrict__ x2dual,
    const int* __restrict__ list, const int* __restrict__ counters){
  int n = counters[0];
  int row0 = blockIdx.x * 64;
  if (row0 >= n) return;
  __shared__ float Xsh[64][129];
  __shared__ float Wsh[128][65];
  for (int i = threadIdx.x; i < 64*64; i += 256){
    int a = i >> 6, j = i & 63;
    Wsh[j][a] = Wa[i];
    Wsh[64 + j][a] = Wb[i];
  }
  for (int i = threadIdx.x; i < 64*128; i += 256){
    int r = i >> 7, c = i & 127;
    int idx = row0 + r;
    float v = 0.f;
    if (idx < n){
      int row = list[idx];
      v = (c < 64) ? kg[(size_t)row*64 + c] : collab[(size_t)row*64 + (c - 64)];
    }
    Xsh[r][c] = v;
  }
  __syncthreads();
  int ct = threadIdx.x & 15, rt = threadIdx.x >> 4;
  int r0 = rt * 4, c0 = ct * 4;
  float acc[4][4] = {};
  for (int k = 0; k < 128; ++k){
    float w0 = Wsh[k][c0], w1 = Wsh[k][c0+1], w2 = Wsh[k][c0+2], w3 = Wsh[k][c0+3];
    #pragma unroll
    for (int i = 0; i < 4; ++i){
      float x = Xsh[r0+i][k];
      acc[i][0] += x*w0; acc[i][1] += x*w1; acc[i][2] += x*w2; acc[i][3] += x*w3;
    }
  }
  #pragma unroll
  for (int i = 0; i < 4; ++i){
    int idx = row0 + r0 + i;
    if (idx < n){
      int row = list[idx];
      float4 o;
      #pragma unroll
      for (int j = 0; j < 4; ++j){
        int c = c0 + j;
        float g = 1.f / (1.f + __expf(-acc[i][j]));
        float kv = Xsh[r0+i][c];
        float cv = Xsh[r0+i][64 + c];
        (&o.x)[j] = g*kv + (1.f - g)*cv;
      }
      *(float4*)&x2dual[(size_t)row*64 + c0] = o;
    }
  }
}

// fused spmm-2 + gather: 3072 output rows directly into user_e / item_e.
__global__ void __launch_bounds__(256) k_spmm2g(const int* __restrict__ row_ptr,
    const int* __restrict__ cnt_end, const int* __restrict__ csr_col,
    const float* __restrict__ csr_val, const float4* __restrict__ x2_4,
    const float4* __restrict__ all4, const float4* __restrict__ collab4,
    const int* __restrict__ user_ids, const int* __restrict__ item_ids,
    float4* __restrict__ user_e, float4* __restrict__ item_e){
  int sub = threadIdx.x & 15;
  int g = (blockIdx.x*256 + threadIdx.x) >> 4;
  if (g >= 3072) return;
  int id;
  float4 b1;
  if (g < 1024){
    id = user_ids[g];                         // >= N_ENT
    b1 = x2_4[(size_t)id*16 + sub];           // users1 lives in x2
  } else {
    id = item_ids[g - 1024];
    b1 = collab4[(size_t)id*16 + sub];
  }
  float4 b0 = all4[(size_t)id*16 + sub];
  float4 acc = {b0.x+b1.x, b0.y+b1.y, b0.z+b1.z, b0.w+b1.w};
  int beg = row_ptr[id], end = cnt_end[id];
  for (int e = beg; e < end; ++e){
    int c = csr_col[e];
    float v = csr_val[e];
    float4 s = x2_4[(size_t)c*16 + sub];
    acc.x += v*s.x; acc.y += v*s.y; acc.z += v*s.z; acc.w += v*s.w;
  }
  if (g < 1024) user_e[(size_t)g*16 + sub] = acc;
  else item_e[(size_t)(g - 1024)*16 + sub] = acc;
}

// out[1024][2048] = user_e @ item_e^T, 32x32 tiles, 2x2 micro-tile, K=64
__global__ void __launch_bounds__(256) k_out(const float* __restrict__ ue,
    const float* __restrict__ ie, float* __restrict__ out){
  __shared__ float ash[32][65];
  __shared__ float bsh[32][65];
  int row0 = blockIdx.y * 32, col0 = blockIdx.x * 32;
  for (int i = threadIdx.x; i < 32*64; i += 256){
    int r = i >> 6, c = i & 63;
    ash[r][c] = ue[(size_t)(row0 + r)*DIM + c];
    bsh[r][c] = ie[(size_t)(col0 + r)*DIM + c];
  }
  __syncthreads();
  int tx = threadIdx.x & 15, ty = threadIdx.x >> 4;
  int r0 = ty*2, c0 = tx*2;
  float a00=0.f, a01=0.f, a10=0.f, a11=0.f;
  #pragma unroll
  for (int k = 0; k < 64; ++k){
    float x0 = ash[r0][k], x1 = ash[r0+1][k];
    float y0 = bsh[c0][k], y1 = bsh[c0+1][k];
    a00 += x0*y0; a01 += x0*y1; a10 += x1*y0; a11 += x1*y1;
  }
  float2 o0 = {a00, a01}, o1 = {a10, a11};
  *(float2*)&out[(size_t)(row0 + r0)*2048 + col0 + c0] = o0;
  *(float2*)&out[(size_t)(row0 + r0 + 1)*2048 + col0 + c0] = o1;
}

extern "C" void kernel_launch(void* const* d_in, const int* in_sizes, int n_in,
                              void* d_out, int out_size, void* d_ws, size_t ws_size,
                              hipStream_t stream){
  const float* all_embed = (const float*)d_in[0];
  const float* rel_embed = (const float*)d_in[1];
  const float* Wk_w      = (const float*)d_in[2];
  const float* Wk_b      = (const float*)d_in[3];
  const float* Wa_w      = (const float*)d_in[4];
  const float* Wb_w      = (const float*)d_in[5];
  const float* a_vals    = (const float*)d_in[6];
  const int* user_ids   = (const int*)d_in[7];
  const int* item_ids   = (const int*)d_in[8];
  const int* h_list     = (const int*)d_in[9];
  const int* t_list     = (const int*)d_in[10];
  const int* r_list     = (const int*)d_in[11];
  const int* a_row      = (const int*)d_in[12];
  const int* a_col      = (const int*)d_in[13];
  float* out = (float*)d_out;

  char* p = (char*)d_ws;
  auto alloc = [&](size_t bytes)->void*{
    void* r = (void*)p;
    p += (bytes + 255) & ~(size_t)255;
    return r;
  };
  float* m_rel   = (float*)alloc((size_t)N_RELC*128*4);
  float* b_rel   = (float*)alloc((size_t)N_RELC*4);
  int*   kg_off  = (int*)  alloc((size_t)(N_ENT+1)*4);
  // zeroed region: cnt | counters | flags
  size_t zbytes = (size_t)N_TOTN*4 + 256 + (2*(size_t)N_ENT + 2*(size_t)N_USR + N_TOTN);
  char*  zbase  = (char*)alloc(zbytes);
  int*   cnt      = (int*)zbase;
  int*   counters = (int*)(zbase + (size_t)N_TOTN*4);
  u8*    r2_item  = (u8*)(zbase + (size_t)N_TOTN*4 + 256);
  u8*    r2_user  = r2_item + N_ENT;
  u8*    need_d   = r2_user + N_USR;
  u8*    need_u   = need_d + N_ENT;
  u8*    row_need = need_u + N_USR;
  int*   row_ptr = (int*)  alloc((size_t)(N_TOTN+1)*4);
  int*   part    = (int*)  alloc((size_t)SCAN_NB*4);
  int*   csr_col = (int*)  alloc((size_t)NA*4);
  float* csr_val = (float*)alloc((size_t)NA*4);
  int*   list_gate = (int*)alloc((size_t)N_ENT*4);
  int*   list_s1   = (int*)alloc((size_t)N_TOTN*4);
  float* kg1     = (float*)alloc((size_t)N_ENT*DIM*4);
  float* collab1 = (float*)alloc((size_t)N_ENT*DIM*4);
  float* x2      = (float*)alloc((size_t)N_TOTN*DIM*4);  // [dual ; users1]
  float* user_e  = (float*)alloc((size_t)1024*DIM*4);
  float* item_e  = (float*)alloc((size_t)2048*DIM*4);

  hipMemsetAsync(zbase, 0, zbytes, stream);
  k_mrel<<<17, 256, 0, stream>>>(rel_embed, Wk_w, Wk_b, m_rel, b_rel);
  k_kgoff<<<(NEDGE + 1 + 255)/256, 256, 0, stream>>>(h_list, kg_off);
  k_r2<<<12, 256, 0, stream>>>(user_ids, item_ids, r2_item, r2_user);
  k_mark<<<(NA + 255)/256, 256, 0, stream>>>(a_row, a_col, r2_item, r2_user, need_d, need_u);
  k_lists<<<SCAN_NB, 256, 0, stream>>>(need_d, need_u, r2_item, r2_user,
      row_need, list_gate, list_s1, counters);
  k_hist<<<(NA + 255)/256, 256, 0, stream>>>(a_row, row_need, cnt);
  k_scan1<<<SCAN_NB, 256, 0, stream>>>(cnt, part);
  k_scan2<<<1, 512, 0, stream>>>(part);
  k_scan3<<<SCAN_NB, 256, 0, stream>>>(cnt, part, row_ptr);
  k_fill<<<(NA + 255)/256, 256, 0, stream>>>(a_row, a_col, a_vals, row_need, cnt, csr_col, csr_val);
  // after k_fill, cnt[r] == row end offset (row_ptr[r] + deg(r)) for needed rows

  k_att<<<512, 256, 0, stream>>>((const float4*)all_embed, (const float4*)m_rel,
      b_rel, kg_off, t_list, r_list, list_gate, counters, (float4*)kg1);
  k_spmm1<<<512, 256, 0, stream>>>(row_ptr, cnt, csr_col, csr_val,
      (const float4*)all_embed, list_s1, counters, (float4*)collab1, (float4*)x2);
  k_gate<<<(N_ENT + 63)/64, 256, 0, stream>>>(kg1, collab1, Wa_w, Wb_w, x2, list_gate, counters);
  k_spmm2g<<<192, 256, 0, stream>>>(row_ptr, cnt, csr_col, csr_val,
      (const float4*)x2, (const float4*)all_embed, (const float4*)collab1,
      user_ids, item_ids, (float4*)user_e, (float4*)item_e);
  dim3 grid_out(2048/32, 1024/32);
  k_out<<<grid_out, 256, 0, stream>>>(user_e, item_e, out);
}

// Round 5
// 271.060 us; speedup vs baseline: 2.7736x; 1.1873x over previous
//
#include <hip/hip_runtime.h>
#include <hip/hip_bf16.h>

#define N_ENT 100000
#define N_USR 30000
#define N_TOTN 130000
#define N_RELC 32
#define DIM 64
#define NEDGE 500000
#define INTER 500000
#define NA 1000000
#define SLOPE 0.01f
#define SCAN_NB 508   // ceil(130000/256)

typedef unsigned char u8;
typedef unsigned long long u64;

__device__ __forceinline__ float grp_sum16(float v){
  v += __shfl_xor(v, 8, 64);
  v += __shfl_xor(v, 4, 64);
  v += __shfl_xor(v, 2, 64);
  v += __shfl_xor(v, 1, 64);
  return v;
}
__device__ __forceinline__ float grp_max16(float v){
  v = fmaxf(v, __shfl_xor(v, 8, 64));
  v = fmaxf(v, __shfl_xor(v, 4, 64));
  v = fmaxf(v, __shfl_xor(v, 2, 64));
  v = fmaxf(v, __shfl_xor(v, 1, 64));
  return v;
}

// fused: m_rel/b_rel precompute + r2 output-row flags + kg segment offsets
__global__ void __launch_bounds__(256) k_prep(
    const float* __restrict__ rel, const float* __restrict__ Wk,
    const float* __restrict__ Wkb, float* __restrict__ m, float* __restrict__ b,
    const int* __restrict__ h_list, int* __restrict__ off,
    const int* __restrict__ user_ids, const int* __restrict__ item_ids,
    u8* __restrict__ r2_item, u8* __restrict__ r2_user){
  int bid = blockIdx.x;
  if (bid < 17){
    int idx = bid*256 + threadIdx.x;
    if (idx < N_RELC*128){
      int r = idx >> 7, j = idx & 127;
      float s = 0.f;
      for (int d = 0; d < DIM; ++d) s += rel[r*DIM+d] * Wk[d*128+j];
      m[idx] = s;
    } else if (idx < N_RELC*128 + N_RELC){
      int r = idx - N_RELC*128;
      float s = 0.f;
      for (int d = 0; d < DIM; ++d) s += Wkb[d] * rel[r*DIM+d];
      b[r] = s;
    }
  } else if (bid < 29){
    int i = (bid - 17)*256 + threadIdx.x;
    if (i < 1024) r2_user[user_ids[i] - N_ENT] = 1;
    else if (i < 3072) r2_item[item_ids[i - 1024]] = 1;
  } else {
    int e = (bid - 29)*256 + threadIdx.x;
    if (e <= NEDGE){
      int hc = (e < NEDGE) ? h_list[e] : N_ENT;
      int hp = (e == 0) ? -1 : h_list[e-1];
      for (int s = hp+1; s <= hc; ++s) off[s] = e;
    }
  }
}

// mark spmm-2 input columns using bipartite symmetry: pair k = (it, N_ENT+u)
__global__ void k_mark(const int* __restrict__ a_row, const int* __restrict__ a_col,
                       const u8* __restrict__ r2_item, const u8* __restrict__ r2_user,
                       u8* __restrict__ need_d, u8* __restrict__ need_u){
  int i = blockIdx.x*256 + threadIdx.x;
  if (i >= INTER) return;
  int it = a_row[i];            // < N_ENT
  int uu = a_col[i] - N_ENT;    // user index
  if (r2_item[it]) need_u[uu] = 1;
  if (r2_user[uu]) need_d[it] = 1;
}

// compact row lists + row_need flags
__global__ void k_lists(const u8* __restrict__ need_d, const u8* __restrict__ need_u,
                        const u8* __restrict__ r2_item, const u8* __restrict__ r2_user,
                        u8* __restrict__ row_need, int* __restrict__ list_gate,
                        int* __restrict__ list_s1, int* __restrict__ counters){
  int i = blockIdx.x*256 + threadIdx.x;
  int lane = threadIdx.x & 63;
  bool pg = false, ps = false;
  if (i < N_TOTN){
    if (i < N_ENT){ pg = need_d[i] != 0; ps = pg || (r2_item[i] != 0); }
    else { int u = i - N_ENT; ps = (need_u[u] != 0) || (r2_user[u] != 0); }
    row_need[i] = ps ? 1 : 0;
  }
  u64 mg = __ballot(pg);
  if (mg){
    int leader = __ffsll(mg) - 1;
    int base = 0;
    if (lane == leader) base = atomicAdd(&counters[0], __popcll(mg));
    base = __shfl(base, leader, 64);
    if (pg) list_gate[base + __popcll(mg & ((1ull << lane) - 1))] = i;
  }
  u64 ms = __ballot(ps);
  if (ms){
    int leader = __ffsll(ms) - 1;
    int base = 0;
    if (lane == leader) base = atomicAdd(&counters[1], __popcll(ms));
    base = __shfl(base, leader, 64);
    if (ps) list_s1[base + __popcll(ms & ((1ull << lane) - 1))] = i;
  }
}

// degree histogram over needed rows (500k pairs, both directions per pair)
__global__ void k_hist(const int* __restrict__ a_row, const int* __restrict__ a_col,
                       const u8* __restrict__ row_need, int* __restrict__ cnt){
  int i = blockIdx.x*256 + threadIdx.x;
  if (i >= INTER) return;
  int it = a_row[i];
  int uc = a_col[i];
  if (row_need[it]) atomicAdd(&cnt[it], 1);
  if (row_need[uc]) atomicAdd(&cnt[uc], 1);
}

__global__ void k_scan1(const int* __restrict__ cnt, int* __restrict__ part){
  __shared__ int sh[256];
  int idx = blockIdx.x*256 + threadIdx.x;
  sh[threadIdx.x] = (idx < N_TOTN) ? cnt[idx] : 0;
  __syncthreads();
  for (int o = 128; o > 0; o >>= 1){
    if (threadIdx.x < o) sh[threadIdx.x] += sh[threadIdx.x + o];
    __syncthreads();
  }
  if (threadIdx.x == 0) part[blockIdx.x] = sh[0];
}

// per-block: reduce own prefix of part[], then local exclusive scan (scan2 folded in)
__global__ void k_scan3(int* __restrict__ cnt, const int* __restrict__ part,
                        int* __restrict__ row_ptr){
  __shared__ int sh[256];
  int t = threadIdx.x;
  int s = 0;
  for (int j = t; j < blockIdx.x; j += 256) s += part[j];
  sh[t] = s;
  __syncthreads();
  for (int o = 128; o > 0; o >>= 1){
    if (t < o) sh[t] += sh[t + o];
    __syncthreads();
  }
  int base = sh[0];
  __syncthreads();
  int idx = blockIdx.x*256 + t;
  int v = (idx < N_TOTN) ? cnt[idx] : 0;
  sh[t] = v;
  __syncthreads();
  for (int o = 1; o < 256; o <<= 1){
    int a = (t >= o) ? sh[t - o] : 0;
    __syncthreads();
    sh[t] += a;
    __syncthreads();
  }
  int excl = base + sh[t] - v;
  if (idx < N_TOTN){ row_ptr[idx] = excl; cnt[idx] = excl; }
}

// CSR fill, 500k pairs, both directions (vals differ per direction)
__global__ void k_fill(const int* __restrict__ a_row, const int* __restrict__ a_col,
                       const float* __restrict__ a_vals, const u8* __restrict__ row_need,
                       int* __restrict__ pos, int* __restrict__ csr_col, float* __restrict__ csr_val){
  int i = blockIdx.x*256 + threadIdx.x;
  if (i >= INTER) return;
  int it = a_row[i];
  int uc = a_col[i];
  if (row_need[it]){
    int p = atomicAdd(&pos[it], 1);
    csr_col[p] = uc;
    csr_val[p] = a_vals[i];
  }
  if (row_need[uc]){
    int p = atomicAdd(&pos[uc], 1);
    csr_col[p] = it;
    csr_val[p] = a_vals[i + INTER];
  }
}

// fused logits + chunked segment softmax + aggregation. 16-lane group per head.
__global__ void __launch_bounds__(256) k_att(const float4* __restrict__ ent4,
    const float4* __restrict__ m4, const float* __restrict__ bvec,
    const int* __restrict__ off, const int* __restrict__ t_list,
    const int* __restrict__ r_list, const int* __restrict__ list,
    const int* __restrict__ counters, float4* __restrict__ kg4){
  __shared__ float4 msh[N_RELC*32];
  __shared__ float bsh[N_RELC];
  for (int i = threadIdx.x; i < N_RELC*32; i += 256) msh[i] = m4[i];
  if (threadIdx.x < N_RELC) bsh[threadIdx.x] = bvec[threadIdx.x];
  __syncthreads();
  int n = counters[0];
  int sub = threadIdx.x & 15;
  int grp = (blockIdx.x*256 + threadIdx.x) >> 4;
  int ng = (gridDim.x*256) >> 4;
  for (int idx = grp; idx < n; idx += ng){
    int s = list[idx];
    int beg = off[s], end = off[s+1];
    float4 h4 = ent4[(size_t)s*16 + sub];
    float run_m = -INFINITY, run_l = 0.f;
    float4 acc = {0.f,0.f,0.f,0.f};
    for (int base = beg; base < end; base += 16){
      int mch = end - base; if (mch > 16) mch = 16;
      int tj = 0, rj = 0;
      if (sub < mch){ tj = t_list[base + sub]; rj = r_list[base + sub]; }
      float logit_mine = -INFINITY;
      #pragma unroll 4
      for (int j = 0; j < mch; ++j){
        int ti = __shfl(tj, j, 16);
        int r  = __shfl(rj, j, 16);
        float4 t4 = ent4[(size_t)ti*16 + sub];
        float4 mt = msh[r*32 + sub];
        float4 mh = msh[r*32 + 16 + sub];
        float v = t4.x*mt.x + t4.y*mt.y + t4.z*mt.z + t4.w*mt.w
                + h4.x*mh.x + h4.y*mh.y + h4.z*mh.z + h4.w*mh.w;
        v = grp_sum16(v) + bsh[r];
        v = (v >= 0.f) ? v : SLOPE * v;
        if (sub == j) logit_mine = v;
      }
      float cmax = grp_max16(logit_mine);
      float nm = fmaxf(run_m, cmax);
      float al = __expf(run_m - nm);   // first chunk: exp(-inf)=0
      run_l *= al;
      acc.x *= al; acc.y *= al; acc.z *= al; acc.w *= al;
      #pragma unroll 4
      for (int j = 0; j < mch; ++j){
        float lg = __shfl(logit_mine, j, 16);
        int ti = __shfl(tj, j, 16);
        float w = __expf(lg - nm);
        float4 t4 = ent4[(size_t)ti*16 + sub];   // cache-hot re-gather
        run_l += w;
        acc.x += w*t4.x; acc.y += w*t4.y; acc.z += w*t4.z; acc.w += w*t4.w;
      }
      run_m = nm;
    }
    float inv = (end > beg) ? 1.f / run_l : 0.f;
    float4 o = {acc.x*inv, acc.y*inv, acc.z*inv, acc.w*inv};
    kg4[(size_t)s*16 + sub] = o;
  }
}

// restricted CSR SpMM layer 1, cooperative col/val loads. 16-lane group per row.
__global__ void __launch_bounds__(256) k_spmm1(const int* __restrict__ row_ptr,
    const int* __restrict__ cnt_end, const int* __restrict__ csr_col,
    const float* __restrict__ csr_val, const float4* __restrict__ src4,
    const int* __restrict__ list, const int* __restrict__ counters,
    float4* __restrict__ collab4, float4* __restrict__ x2_4){
  int n = counters[1];
  int sub = threadIdx.x & 15;
  int grp = (blockIdx.x*256 + threadIdx.x) >> 4;
  int ng = (gridDim.x*256) >> 4;
  for (int idx = grp; idx < n; idx += ng){
    int i = list[idx];
    int beg = row_ptr[i], end = cnt_end[i];
    float4 acc = {0.f,0.f,0.f,0.f};
    for (int base = beg; base < end; base += 16){
      int mch = end - base; if (mch > 16) mch = 16;
      int c = 0; float v = 0.f;
      if (sub < mch){ c = csr_col[base + sub]; v = csr_val[base + sub]; }
      #pragma unroll 4
      for (int j = 0; j < mch; ++j){
        int cj = __shfl(c, j, 16);
        float vj = __shfl(v, j, 16);
        float4 s = src4[(size_t)cj*16 + sub];
        acc.x += vj*s.x; acc.y += vj*s.y; acc.z += vj*s.z; acc.w += vj*s.w;
      }
    }
    if (i < N_ENT) collab4[(size_t)i*16 + sub] = acc;
    else x2_4[(size_t)i*16 + sub] = acc;
  }
}

// gate over list rows: dual = g*kg + (1-g)*collab -> x2 rows < N_ENT
__global__ void __launch_bounds__(256) k_gate(const float* __restrict__ kg,
    const float* __restrict__ collab, const float* __restrict__ Wa,
    const float* __restrict__ Wb, float* __restrict__ x2dual,
    const int* __restrict__ list, const int* __restrict__ counters){
  int n = counters[0];
  int row0 = blockIdx.x * 64;
  if (row0 >= n) return;
  __shared__ float Xsh[64][129];
  __shared__ float Wsh[128][65];
  for (int i = threadIdx.x; i < 64*64; i += 256){
    int a = i >> 6, j = i & 63;
    Wsh[j][a] = Wa[i];
    Wsh[64 + j][a] = Wb[i];
  }
  for (int i = threadIdx.x; i < 64*128; i += 256){
    int r = i >> 7, c = i & 127;
    int idx = row0 + r;
    float v = 0.f;
    if (idx < n){
      int row = list[idx];
      v = (c < 64) ? kg[(size_t)row*64 + c] : collab[(size_t)row*64 + (c - 64)];
    }
    Xsh[r][c] = v;
  }
  __syncthreads();
  int ct = threadIdx.x & 15, rt = threadIdx.x >> 4;
  int r0 = rt * 4, c0 = ct * 4;
  float acc[4][4] = {};
  for (int k = 0; k < 128; ++k){
    float w0 = Wsh[k][c0], w1 = Wsh[k][c0+1], w2 = Wsh[k][c0+2], w3 = Wsh[k][c0+3];
    #pragma unroll
    for (int i = 0; i < 4; ++i){
      float x = Xsh[r0+i][k];
      acc[i][0] += x*w0; acc[i][1] += x*w1; acc[i][2] += x*w2; acc[i][3] += x*w3;
    }
  }
  #pragma unroll
  for (int i = 0; i < 4; ++i){
    int idx = row0 + r0 + i;
    if (idx < n){
      int row = list[idx];
      float4 o;
      #pragma unroll
      for (int j = 0; j < 4; ++j){
        int c = c0 + j;
        float g = 1.f / (1.f + __expf(-acc[i][j]));
        float kv = Xsh[r0+i][c];
        float cv = Xsh[r0+i][64 + c];
        (&o.x)[j] = g*kv + (1.f - g)*cv;
      }
      *(float4*)&x2dual[(size_t)row*64 + c0] = o;
    }
  }
}

// fused spmm-2 + gather: one 64-lane wave per output row, lane = dim.
__global__ void __launch_bounds__(256) k_spmm2g(const int* __restrict__ row_ptr,
    const int* __restrict__ cnt_end, const int* __restrict__ csr_col,
    const float* __restrict__ csr_val, const float* __restrict__ x2,
    const float* __restrict__ all_embed, const float* __restrict__ collab1,
    const int* __restrict__ user_ids, const int* __restrict__ item_ids,
    float* __restrict__ user_e, float* __restrict__ item_e){
  int lane = threadIdx.x & 63;
  int g = (blockIdx.x*256 + threadIdx.x) >> 6;
  if (g >= 3072) return;
  int id;
  float b1;
  if (g < 1024){
    id = user_ids[g];                            // >= N_ENT
    b1 = x2[(size_t)id*64 + lane];               // users1 lives in x2
  } else {
    id = item_ids[g - 1024];
    b1 = collab1[(size_t)id*64 + lane];
  }
  float acc = all_embed[(size_t)id*64 + lane] + b1;
  int beg = row_ptr[id], end = cnt_end[id];
  for (int base = beg; base < end; base += 64){
    int mch = end - base; if (mch > 64) mch = 64;
    int c = 0; float v = 0.f;
    if (lane < mch){ c = csr_col[base + lane]; v = csr_val[base + lane]; }
    #pragma unroll 4
    for (int j = 0; j < mch; ++j){
      int cj = __shfl(c, j, 64);
      float vj = __shfl(v, j, 64);
      acc += vj * x2[(size_t)cj*64 + lane];
    }
  }
  if (g < 1024) user_e[(size_t)g*64 + lane] = acc;
  else item_e[(size_t)(g - 1024)*64 + lane] = acc;
}

// out[1024][2048] = user_e @ item_e^T, 32x32 tiles, 2x2 micro-tile, K=64
__global__ void __launch_bounds__(256) k_out(const float* __restrict__ ue,
    const float* __restrict__ ie, float* __restrict__ out){
  __shared__ float ash[32][65];
  __shared__ float bsh[32][65];
  int row0 = blockIdx.y * 32, col0 = blockIdx.x * 32;
  for (int i = threadIdx.x; i < 32*64; i += 256){
    int r = i >> 6, c = i & 63;
    ash[r][c] = ue[(size_t)(row0 + r)*DIM + c];
    bsh[r][c] = ie[(size_t)(col0 + r)*DIM + c];
  }
  __syncthreads();
  int tx = threadIdx.x & 15, ty = threadIdx.x >> 4;
  int r0 = ty*2, c0 = tx*2;
  float a00=0.f, a01=0.f, a10=0.f, a11=0.f;
  #pragma unroll
  for (int k = 0; k < 64; ++k){
    float x0 = ash[r0][k], x1 = ash[r0+1][k];
    float y0 = bsh[c0][k], y1 = bsh[c0+1][k];
    a00 += x0*y0; a01 += x0*y1; a10 += x1*y0; a11 += x1*y1;
  }
  float2 o0 = {a00, a01}, o1 = {a10, a11};
  *(float2*)&out[(size_t)(row0 + r0)*2048 + col0 + c0] = o0;
  *(float2*)&out[(size_t)(row0 + r0 + 1)*2048 + col0 + c0] = o1;
}

extern "C" void kernel_launch(void* const* d_in, const int* in_sizes, int n_in,
                              void* d_out, int out_size, void* d_ws, size_t ws_size,
                              hipStream_t stream){
  const float* all_embed = (const float*)d_in[0];
  const float* rel_embed = (const float*)d_in[1];
  const float* Wk_w      = (const float*)d_in[2];
  const float* Wk_b      = (const float*)d_in[3];
  const float* Wa_w      = (const float*)d_in[4];
  const float* Wb_w      = (const float*)d_in[5];
  const float* a_vals    = (const float*)d_in[6];
  const int* user_ids   = (const int*)d_in[7];
  const int* item_ids   = (const int*)d_in[8];
  const int* h_list     = (const int*)d_in[9];
  const int* t_list     = (const int*)d_in[10];
  const int* r_list     = (const int*)d_in[11];
  const int* a_row      = (const int*)d_in[12];
  const int* a_col      = (const int*)d_in[13];
  float* out = (float*)d_out;

  char* p = (char*)d_ws;
  auto alloc = [&](size_t bytes)->void*{
    void* r = (void*)p;
    p += (bytes + 255) & ~(size_t)255;
    return r;
  };
  float* m_rel   = (float*)alloc((size_t)N_RELC*128*4);
  float* b_rel   = (float*)alloc((size_t)N_RELC*4);
  int*   kg_off  = (int*)  alloc((size_t)(N_ENT+1)*4);
  size_t zbytes = (size_t)N_TOTN*4 + 256 + (2*(size_t)N_ENT + 2*(size_t)N_USR + N_TOTN);
  char*  zbase  = (char*)alloc(zbytes);
  int*   cnt      = (int*)zbase;
  int*   counters = (int*)(zbase + (size_t)N_TOTN*4);
  u8*    r2_item  = (u8*)(zbase + (size_t)N_TOTN*4 + 256);
  u8*    r2_user  = r2_item + N_ENT;
  u8*    need_d   = r2_user + N_USR;
  u8*    need_u   = need_d + N_ENT;
  u8*    row_need = need_u + N_USR;
  int*   row_ptr = (int*)  alloc((size_t)(N_TOTN+1)*4);
  int*   part    = (int*)  alloc((size_t)SCAN_NB*4);
  int*   csr_col = (int*)  alloc((size_t)NA*4);
  float* csr_val = (float*)alloc((size_t)NA*4);
  int*   list_gate = (int*)alloc((size_t)N_ENT*4);
  int*   list_s1   = (int*)alloc((size_t)N_TOTN*4);
  float* kg1     = (float*)alloc((size_t)N_ENT*DIM*4);
  float* collab1 = (float*)alloc((size_t)N_ENT*DIM*4);
  float* x2      = (float*)alloc((size_t)N_TOTN*DIM*4);  // [dual ; users1]
  float* user_e  = (float*)alloc((size_t)1024*DIM*4);
  float* item_e  = (float*)alloc((size_t)2048*DIM*4);

  hipMemsetAsync(zbase, 0, zbytes, stream);
  k_prep<<<29 + (NEDGE + 1 + 255)/256, 256, 0, stream>>>(rel_embed, Wk_w, Wk_b,
      m_rel, b_rel, h_list, kg_off, user_ids, item_ids, r2_item, r2_user);
  k_mark<<<(INTER + 255)/256, 256, 0, stream>>>(a_row, a_col, r2_item, r2_user, need_d, need_u);
  k_lists<<<SCAN_NB, 256, 0, stream>>>(need_d, need_u, r2_item, r2_user,
      row_need, list_gate, list_s1, counters);
  k_hist<<<(INTER + 255)/256, 256, 0, stream>>>(a_row, a_col, row_need, cnt);
  k_scan1<<<SCAN_NB, 256, 0, stream>>>(cnt, part);
  k_scan3<<<SCAN_NB, 256, 0, stream>>>(cnt, part, row_ptr);
  k_fill<<<(INTER + 255)/256, 256, 0, stream>>>(a_row, a_col, a_vals, row_need,
      cnt, csr_col, csr_val);
  // after k_fill, cnt[r] == row_ptr[r] + deg(r) for needed rows

  k_att<<<2048, 256, 0, stream>>>((const float4*)all_embed, (const float4*)m_rel,
      b_rel, kg_off, t_list, r_list, list_gate, counters, (float4*)kg1);
  k_spmm1<<<2048, 256, 0, stream>>>(row_ptr, cnt, csr_col, csr_val,
      (const float4*)all_embed, list_s1, counters, (float4*)collab1, (float4*)x2);
  k_gate<<<(N_ENT + 63)/64, 256, 0, stream>>>(kg1, collab1, Wa_w, Wb_w, x2,
      list_gate, counters);
  k_spmm2g<<<768, 256, 0, stream>>>(row_ptr, cnt, csr_col, csr_val,
      x2, all_embed, collab1, user_ids, item_ids, user_e, item_e);
  dim3 grid_out(2048/32, 1024/32);
  k_out<<<grid_out, 256, 0, stream>>>(user_e, item_e, out);
}

// Round 6
// 224.533 us; speedup vs baseline: 3.3483x; 1.2072x over previous
//
#include <hip/hip_runtime.h>
#include <hip/hip_bf16.h>

#define N_ENT 100000
#define N_USR 30000
#define N_TOTN 130000
#define N_RELC 32
#define DIM 64
#define NEDGE 500000
#define INTER 500000
#define NA 1000000
#define SLOPE 0.01f
#define SCAN_NB 508   // ceil(130000/256)
#define CPT_NB 127    // compaction blocks: 127*1024 = 130048 >= 130000
#define ATT_NB 1024   // att blocks inside fused k_l1

typedef unsigned char u8;
typedef unsigned long long u64;

__device__ __forceinline__ float grp_sum16(float v){
  v += __shfl_xor(v, 8, 64);
  v += __shfl_xor(v, 4, 64);
  v += __shfl_xor(v, 2, 64);
  v += __shfl_xor(v, 1, 64);
  return v;
}
__device__ __forceinline__ float grp_max16(float v){
  v = fmaxf(v, __shfl_xor(v, 8, 64));
  v = fmaxf(v, __shfl_xor(v, 4, 64));
  v = fmaxf(v, __shfl_xor(v, 2, 64));
  v = fmaxf(v, __shfl_xor(v, 1, 64));
  return v;
}

// fused: m_rel/b_rel precompute + r2 output-row flags + kg segment offsets
__global__ void __launch_bounds__(256) k_prep(
    const float* __restrict__ rel, const float* __restrict__ Wk,
    const float* __restrict__ Wkb, float* __restrict__ m, float* __restrict__ b,
    const int* __restrict__ h_list, int* __restrict__ off,
    const int* __restrict__ user_ids, const int* __restrict__ item_ids,
    u8* __restrict__ r2_item, u8* __restrict__ r2_user){
  int bid = blockIdx.x;
  if (bid < 17){
    int idx = bid*256 + threadIdx.x;
    if (idx < N_RELC*128){
      int r = idx >> 7, j = idx & 127;
      float s = 0.f;
      for (int d = 0; d < DIM; ++d) s += rel[r*DIM+d] * Wk[d*128+j];
      m[idx] = s;
    } else if (idx < N_RELC*128 + N_RELC){
      int r = idx - N_RELC*128;
      float s = 0.f;
      for (int d = 0; d < DIM; ++d) s += Wkb[d] * rel[r*DIM+d];
      b[r] = s;
    }
  } else if (bid < 29){
    int i = (bid - 17)*256 + threadIdx.x;
    if (i < 1024) r2_user[user_ids[i] - N_ENT] = 1;
    else if (i < 3072) r2_item[item_ids[i - 1024]] = 1;
  } else {
    int e = (bid - 29)*256 + threadIdx.x;
    if (e <= NEDGE){
      int hc = (e < NEDGE) ? h_list[e] : N_ENT;
      int hp = (e == 0) ? -1 : h_list[e-1];
      for (int s = hp+1; s <= hc; ++s) off[s] = e;
    }
  }
}

// mark spmm-2 input columns using bipartite symmetry: pair k = (it, N_ENT+u)
__global__ void k_mark(const int* __restrict__ a_row, const int* __restrict__ a_col,
                       const u8* __restrict__ r2_item, const u8* __restrict__ r2_user,
                       u8* __restrict__ need_d, u8* __restrict__ need_u){
  int i = blockIdx.x*256 + threadIdx.x;
  if (i >= INTER) return;
  int it = a_row[i];            // < N_ENT
  int uu = a_col[i] - N_ENT;    // user index
  if (r2_item[it]) need_u[uu] = 1;
  if (r2_user[uu]) need_d[it] = 1;
}

// fused: list compaction (blocks < CPT_NB, block-aggregated atomics)
//      + degree histogram (remaining blocks, flags read inline)
__global__ void __launch_bounds__(256) k_build(
    const int* __restrict__ a_row, const int* __restrict__ a_col,
    const u8* __restrict__ need_d, const u8* __restrict__ need_u,
    const u8* __restrict__ r2_item, const u8* __restrict__ r2_user,
    int* __restrict__ list_gate, int* __restrict__ list_s1,
    int* __restrict__ counters, int* __restrict__ cnt){
  if (blockIdx.x < CPT_NB){
    __shared__ u64 mg_sh[16], ms_sh[16];
    __shared__ int pre_g[16], pre_s[16];
    __shared__ int base_sh[2];
    int t = threadIdx.x;
    int wave = t >> 6, lane = t & 63;
    bool pg[4], ps[4];
    int ibase = blockIdx.x*1024;
    #pragma unroll
    for (int k = 0; k < 4; ++k){
      int i = ibase + k*256 + t;
      bool g = false, s = false;
      if (i < N_TOTN){
        if (i < N_ENT){ g = need_d[i] != 0; s = g || (r2_item[i] != 0); }
        else { int u = i - N_ENT; s = (need_u[u] != 0) || (r2_user[u] != 0); }
      }
      pg[k] = g; ps[k] = s;
      u64 mg = __ballot(g), ms = __ballot(s);
      if (lane == 0){ mg_sh[k*4 + wave] = mg; ms_sh[k*4 + wave] = ms; }
    }
    __syncthreads();
    if (t == 0){
      int sg = 0, ss = 0;
      for (int j = 0; j < 16; ++j){
        pre_g[j] = sg; sg += __popcll(mg_sh[j]);
        pre_s[j] = ss; ss += __popcll(ms_sh[j]);
      }
      base_sh[0] = sg ? atomicAdd(&counters[0], sg) : 0;
      base_sh[1] = ss ? atomicAdd(&counters[1], ss) : 0;
    }
    __syncthreads();
    int bg = base_sh[0], bs = base_sh[1];
    u64 lmask = (1ull << lane) - 1;
    #pragma unroll
    for (int k = 0; k < 4; ++k){
      int i = ibase + k*256 + t;
      if (pg[k]) list_gate[bg + pre_g[k*4+wave] + __popcll(mg_sh[k*4+wave] & lmask)] = i;
      if (ps[k]) list_s1 [bs + pre_s[k*4+wave] + __popcll(ms_sh[k*4+wave] & lmask)] = i;
    }
  } else {
    int nb = gridDim.x - CPT_NB;
    for (int i = (blockIdx.x - CPT_NB)*256 + threadIdx.x; i < INTER; i += nb*256){
      int it = a_row[i];
      int uc = a_col[i];
      int uu = uc - N_ENT;
      if (need_d[it] | r2_item[it]) atomicAdd(&cnt[it], 1);
      if (need_u[uu] | r2_user[uu]) atomicAdd(&cnt[uc], 1);
    }
  }
}

__global__ void k_scan1(const int* __restrict__ cnt, int* __restrict__ part){
  __shared__ int sh[256];
  int idx = blockIdx.x*256 + threadIdx.x;
  sh[threadIdx.x] = (idx < N_TOTN) ? cnt[idx] : 0;
  __syncthreads();
  for (int o = 128; o > 0; o >>= 1){
    if (threadIdx.x < o) sh[threadIdx.x] += sh[threadIdx.x + o];
    __syncthreads();
  }
  if (threadIdx.x == 0) part[blockIdx.x] = sh[0];
}

// per-block: reduce own prefix of part[], then local exclusive scan
__global__ void k_scan3(int* __restrict__ cnt, const int* __restrict__ part,
                        int* __restrict__ row_ptr){
  __shared__ int sh[256];
  int t = threadIdx.x;
  int s = 0;
  for (int j = t; j < blockIdx.x; j += 256) s += part[j];
  sh[t] = s;
  __syncthreads();
  for (int o = 128; o > 0; o >>= 1){
    if (t < o) sh[t] += sh[t + o];
    __syncthreads();
  }
  int base = sh[0];
  __syncthreads();
  int idx = blockIdx.x*256 + t;
  int v = (idx < N_TOTN) ? cnt[idx] : 0;
  sh[t] = v;
  __syncthreads();
  for (int o = 1; o < 256; o <<= 1){
    int a = (t >= o) ? sh[t - o] : 0;
    __syncthreads();
    sh[t] += a;
    __syncthreads();
  }
  int excl = base + sh[t] - v;
  if (idx < N_TOTN){ row_ptr[idx] = excl; cnt[idx] = excl; }
}

// CSR fill, 500k pairs, both directions, flags read inline
__global__ void k_fill(const int* __restrict__ a_row, const int* __restrict__ a_col,
                       const float* __restrict__ a_vals,
                       const u8* __restrict__ need_d, const u8* __restrict__ need_u,
                       const u8* __restrict__ r2_item, const u8* __restrict__ r2_user,
                       int* __restrict__ pos, int* __restrict__ csr_col, float* __restrict__ csr_val){
  int i = blockIdx.x*256 + threadIdx.x;
  if (i >= INTER) return;
  int it = a_row[i];
  int uc = a_col[i];
  int uu = uc - N_ENT;
  if (need_d[it] | r2_item[it]){
    int p = atomicAdd(&pos[it], 1);
    csr_col[p] = uc;
    csr_val[p] = a_vals[i];
  }
  if (need_u[uu] | r2_user[uu]){
    int p = atomicAdd(&pos[uc], 1);
    csr_col[p] = it;
    csr_val[p] = a_vals[i + INTER];
  }
}

// fused layer-1: blocks < ATT_NB run attention, the rest run restricted SpMM.
__global__ void __launch_bounds__(256) k_l1(const float4* __restrict__ ent4,
    const float4* __restrict__ m4, const float* __restrict__ bvec,
    const int* __restrict__ off, const int* __restrict__ t_list,
    const int* __restrict__ r_list, const int* __restrict__ list_gate,
    const int* __restrict__ list_s1, const int* __restrict__ counters,
    float4* __restrict__ kg4,
    const int* __restrict__ row_ptr, const int* __restrict__ cnt_end,
    const int* __restrict__ csr_col, const float* __restrict__ csr_val,
    float4* __restrict__ collab4, float4* __restrict__ x2_4){
  if (blockIdx.x < ATT_NB){
    __shared__ float4 msh[N_RELC*32];
    __shared__ float bsh[N_RELC];
    for (int i = threadIdx.x; i < N_RELC*32; i += 256) msh[i] = m4[i];
    if (threadIdx.x < N_RELC) bsh[threadIdx.x] = bvec[threadIdx.x];
    __syncthreads();
    int n = counters[0];
    int sub = threadIdx.x & 15;
    int grp = (blockIdx.x*256 + threadIdx.x) >> 4;
    int ng = (ATT_NB*256) >> 4;
    for (int idx = grp; idx < n; idx += ng){
      int s = list_gate[idx];
      int beg = off[s], end = off[s+1];
      float4 h4 = ent4[(size_t)s*16 + sub];
      float run_m = -INFINITY, run_l = 0.f;
      float4 acc = {0.f,0.f,0.f,0.f};
      for (int base = beg; base < end; base += 16){
        int mch = end - base; if (mch > 16) mch = 16;
        int tj = 0, rj = 0;
        if (sub < mch){ tj = t_list[base + sub]; rj = r_list[base + sub]; }
        float logit_mine = -INFINITY;
        #pragma unroll 4
        for (int j = 0; j < mch; ++j){
          int ti = __shfl(tj, j, 16);
          int r  = __shfl(rj, j, 16);
          float4 t4 = ent4[(size_t)ti*16 + sub];
          float4 mt = msh[r*32 + sub];
          float4 mh = msh[r*32 + 16 + sub];
          float v = t4.x*mt.x + t4.y*mt.y + t4.z*mt.z + t4.w*mt.w
                  + h4.x*mh.x + h4.y*mh.y + h4.z*mh.z + h4.w*mh.w;
          v = grp_sum16(v) + bsh[r];
          v = (v >= 0.f) ? v : SLOPE * v;
          if (sub == j) logit_mine = v;
        }
        float cmax = grp_max16(logit_mine);
        float nm = fmaxf(run_m, cmax);
        float al = __expf(run_m - nm);   // first chunk: exp(-inf)=0
        run_l *= al;
        acc.x *= al; acc.y *= al; acc.z *= al; acc.w *= al;
        #pragma unroll 4
        for (int j = 0; j < mch; ++j){
          float lg = __shfl(logit_mine, j, 16);
          int ti = __shfl(tj, j, 16);
          float w = __expf(lg - nm);
          float4 t4 = ent4[(size_t)ti*16 + sub];   // cache-hot re-gather
          run_l += w;
          acc.x += w*t4.x; acc.y += w*t4.y; acc.z += w*t4.z; acc.w += w*t4.w;
        }
        run_m = nm;
      }
      float inv = (end > beg) ? 1.f / run_l : 0.f;
      float4 o = {acc.x*inv, acc.y*inv, acc.z*inv, acc.w*inv};
      kg4[(size_t)s*16 + sub] = o;
    }
  } else {
    int n = counters[1];
    int sub = threadIdx.x & 15;
    int bid = blockIdx.x - ATT_NB;
    int nb = gridDim.x - ATT_NB;
    int grp = (bid*256 + threadIdx.x) >> 4;
    int ng = (nb*256) >> 4;
    for (int idx = grp; idx < n; idx += ng){
      int i = list_s1[idx];
      int beg = row_ptr[i], end = cnt_end[i];
      float4 acc = {0.f,0.f,0.f,0.f};
      for (int base = beg; base < end; base += 16){
        int mch = end - base; if (mch > 16) mch = 16;
        int c = 0; float v = 0.f;
        if (sub < mch){ c = csr_col[base + sub]; v = csr_val[base + sub]; }
        #pragma unroll 4
        for (int j = 0; j < mch; ++j){
          int cj = __shfl(c, j, 16);
          float vj = __shfl(v, j, 16);
          float4 sv = ent4[(size_t)cj*16 + sub];   // src = all_embed table
          acc.x += vj*sv.x; acc.y += vj*sv.y; acc.z += vj*sv.z; acc.w += vj*sv.w;
        }
      }
      if (i < N_ENT) collab4[(size_t)i*16 + sub] = acc;
      else x2_4[(size_t)i*16 + sub] = acc;
    }
  }
}

// gate over list rows: dual = g*kg + (1-g)*collab -> x2 rows < N_ENT
__global__ void __launch_bounds__(256) k_gate(const float* __restrict__ kg,
    const float* __restrict__ collab, const float* __restrict__ Wa,
    const float* __restrict__ Wb, float* __restrict__ x2dual,
    const int* __restrict__ list, const int* __restrict__ counters){
  int n = counters[0];
  int row0 = blockIdx.x * 64;
  if (row0 >= n) return;
  __shared__ float Xsh[64][129];
  __shared__ float Wsh[128][65];
  for (int i = threadIdx.x; i < 64*64; i += 256){
    int a = i >> 6, j = i & 63;
    Wsh[j][a] = Wa[i];
    Wsh[64 + j][a] = Wb[i];
  }
  for (int i = threadIdx.x; i < 64*128; i += 256){
    int r = i >> 7, c = i & 127;
    int idx = row0 + r;
    float v = 0.f;
    if (idx < n){
      int row = list[idx];
      v = (c < 64) ? kg[(size_t)row*64 + c] : collab[(size_t)row*64 + (c - 64)];
    }
    Xsh[r][c] = v;
  }
  __syncthreads();
  int ct = threadIdx.x & 15, rt = threadIdx.x >> 4;
  int r0 = rt * 4, c0 = ct * 4;
  float acc[4][4] = {};
  for (int k = 0; k < 128; ++k){
    float w0 = Wsh[k][c0], w1 = Wsh[k][c0+1], w2 = Wsh[k][c0+2], w3 = Wsh[k][c0+3];
    #pragma unroll
    for (int i = 0; i < 4; ++i){
      float x = Xsh[r0+i][k];
      acc[i][0] += x*w0; acc[i][1] += x*w1; acc[i][2] += x*w2; acc[i][3] += x*w3;
    }
  }
  #pragma unroll
  for (int i = 0; i < 4; ++i){
    int idx = row0 + r0 + i;
    if (idx < n){
      int row = list[idx];
      float4 o;
      #pragma unroll
      for (int j = 0; j < 4; ++j){
        int c = c0 + j;
        float g = 1.f / (1.f + __expf(-acc[i][j]));
        float kv = Xsh[r0+i][c];
        float cv = Xsh[r0+i][64 + c];
        (&o.x)[j] = g*kv + (1.f - g)*cv;
      }
      *(float4*)&x2dual[(size_t)row*64 + c0] = o;
    }
  }
}

// fused spmm-2 + gather: one 64-lane wave per output row, lane = dim.
__global__ void __launch_bounds__(256) k_spmm2g(const int* __restrict__ row_ptr,
    const int* __restrict__ cnt_end, const int* __restrict__ csr_col,
    const float* __restrict__ csr_val, const float* __restrict__ x2,
    const float* __restrict__ all_embed, const float* __restrict__ collab1,
    const int* __restrict__ user_ids, const int* __restrict__ item_ids,
    float* __restrict__ user_e, float* __restrict__ item_e){
  int lane = threadIdx.x & 63;
  int g = (blockIdx.x*256 + threadIdx.x) >> 6;
  if (g >= 3072) return;
  int id;
  float b1;
  if (g < 1024){
    id = user_ids[g];                            // >= N_ENT
    b1 = x2[(size_t)id*64 + lane];               // users1 lives in x2
  } else {
    id = item_ids[g - 1024];
    b1 = collab1[(size_t)id*64 + lane];
  }
  float acc = all_embed[(size_t)id*64 + lane] + b1;
  int beg = row_ptr[id], end = cnt_end[id];
  for (int base = beg; base < end; base += 64){
    int mch = end - base; if (mch > 64) mch = 64;
    int c = 0; float v = 0.f;
    if (lane < mch){ c = csr_col[base + lane]; v = csr_val[base + lane]; }
    #pragma unroll 4
    for (int j = 0; j < mch; ++j){
      int cj = __shfl(c, j, 64);
      float vj = __shfl(v, j, 64);
      acc += vj * x2[(size_t)cj*64 + lane];
    }
  }
  if (g < 1024) user_e[(size_t)g*64 + lane] = acc;
  else item_e[(size_t)(g - 1024)*64 + lane] = acc;
}

// out[1024][2048] = user_e @ item_e^T, 32x32 tiles, 2x2 micro-tile, K=64
__global__ void __launch_bounds__(256) k_out(const float* __restrict__ ue,
    const float* __restrict__ ie, float* __restrict__ out){
  __shared__ float ash[32][65];
  __shared__ float bsh[32][65];
  int row0 = blockIdx.y * 32, col0 = blockIdx.x * 32;
  for (int i = threadIdx.x; i < 32*64; i += 256){
    int r = i >> 6, c = i & 63;
    ash[r][c] = ue[(size_t)(row0 + r)*DIM + c];
    bsh[r][c] = ie[(size_t)(col0 + r)*DIM + c];
  }
  __syncthreads();
  int tx = threadIdx.x & 15, ty = threadIdx.x >> 4;
  int r0 = ty*2, c0 = tx*2;
  float a00=0.f, a01=0.f, a10=0.f, a11=0.f;
  #pragma unroll
  for (int k = 0; k < 64; ++k){
    float x0 = ash[r0][k], x1 = ash[r0+1][k];
    float y0 = bsh[c0][k], y1 = bsh[c0+1][k];
    a00 += x0*y0; a01 += x0*y1; a10 += x1*y0; a11 += x1*y1;
  }
  float2 o0 = {a00, a01}, o1 = {a10, a11};
  *(float2*)&out[(size_t)(row0 + r0)*2048 + col0 + c0] = o0;
  *(float2*)&out[(size_t)(row0 + r0 + 1)*2048 + col0 + c0] = o1;
}

extern "C" void kernel_launch(void* const* d_in, const int* in_sizes, int n_in,
                              void* d_out, int out_size, void* d_ws, size_t ws_size,
                              hipStream_t stream){
  const float* all_embed = (const float*)d_in[0];
  const float* rel_embed = (const float*)d_in[1];
  const float* Wk_w      = (const float*)d_in[2];
  const float* Wk_b      = (const float*)d_in[3];
  const float* Wa_w      = (const float*)d_in[4];
  const float* Wb_w      = (const float*)d_in[5];
  const float* a_vals    = (const float*)d_in[6];
  const int* user_ids   = (const int*)d_in[7];
  const int* item_ids   = (const int*)d_in[8];
  const int* h_list     = (const int*)d_in[9];
  const int* t_list     = (const int*)d_in[10];
  const int* r_list     = (const int*)d_in[11];
  const int* a_row      = (const int*)d_in[12];
  const int* a_col      = (const int*)d_in[13];
  float* out = (float*)d_out;

  char* p = (char*)d_ws;
  auto alloc = [&](size_t bytes)->void*{
    void* r = (void*)p;
    p += (bytes + 255) & ~(size_t)255;
    return r;
  };
  float* m_rel   = (float*)alloc((size_t)N_RELC*128*4);
  float* b_rel   = (float*)alloc((size_t)N_RELC*4);
  int*   kg_off  = (int*)  alloc((size_t)(N_ENT+1)*4);
  size_t zbytes = (size_t)N_TOTN*4 + 256 + (2*(size_t)N_ENT + 2*(size_t)N_USR);
  char*  zbase  = (char*)alloc(zbytes);
  int*   cnt      = (int*)zbase;
  int*   counters = (int*)(zbase + (size_t)N_TOTN*4);
  u8*    r2_item  = (u8*)(zbase + (size_t)N_TOTN*4 + 256);
  u8*    r2_user  = r2_item + N_ENT;
  u8*    need_d   = r2_user + N_USR;
  u8*    need_u   = need_d + N_ENT;
  int*   row_ptr = (int*)  alloc((size_t)(N_TOTN+1)*4);
  int*   part    = (int*)  alloc((size_t)SCAN_NB*4);
  int*   csr_col = (int*)  alloc((size_t)NA*4);
  float* csr_val = (float*)alloc((size_t)NA*4);
  int*   list_gate = (int*)alloc((size_t)N_ENT*4);
  int*   list_s1   = (int*)alloc((size_t)N_TOTN*4);
  float* kg1     = (float*)alloc((size_t)N_ENT*DIM*4);
  float* collab1 = (float*)alloc((size_t)N_ENT*DIM*4);
  float* x2      = (float*)alloc((size_t)N_TOTN*DIM*4);  // [dual ; users1]
  float* user_e  = (float*)alloc((size_t)1024*DIM*4);
  float* item_e  = (float*)alloc((size_t)2048*DIM*4);

  hipMemsetAsync(zbase, 0, zbytes, stream);
  k_prep<<<29 + (NEDGE + 1 + 255)/256, 256, 0, stream>>>(rel_embed, Wk_w, Wk_b,
      m_rel, b_rel, h_list, kg_off, user_ids, item_ids, r2_item, r2_user);
  k_mark<<<(INTER + 255)/256, 256, 0, stream>>>(a_row, a_col, r2_item, r2_user, need_d, need_u);
  k_build<<<CPT_NB + 1024, 256, 0, stream>>>(a_row, a_col, need_d, need_u,
      r2_item, r2_user, list_gate, list_s1, counters, cnt);
  k_scan1<<<SCAN_NB, 256, 0, stream>>>(cnt, part);
  k_scan3<<<SCAN_NB, 256, 0, stream>>>(cnt, part, row_ptr);
  k_fill<<<(INTER + 255)/256, 256, 0, stream>>>(a_row, a_col, a_vals,
      need_d, need_u, r2_item, r2_user, cnt, csr_col, csr_val);
  // after k_fill, cnt[r] == row_ptr[r] + deg(r) for needed rows

  k_l1<<<ATT_NB + 2048, 256, 0, stream>>>((const float4*)all_embed,
      (const float4*)m_rel, b_rel, kg_off, t_list, r_list, list_gate, list_s1,
      counters, (float4*)kg1, row_ptr, cnt, csr_col, csr_val,
      (float4*)collab1, (float4*)x2);
  k_gate<<<(N_ENT + 63)/64, 256, 0, stream>>>(kg1, collab1, Wa_w, Wb_w, x2,
      list_gate, counters);
  k_spmm2g<<<768, 256, 0, stream>>>(row_ptr, cnt, csr_col, csr_val,
      x2, all_embed, collab1, user_ids, item_ids, user_e, item_e);
  dim3 grid_out(2048/32, 1024/32);
  k_out<<<grid_out, 256, 0, stream>>>(user_e, item_e, out);
}